// Round 13
// baseline (619.979 us; speedup 1.0000x reference)
//
#include <hip/hip_runtime.h>
#include <cstdint>
#include <cstddef>

#define NN 50000
#define NE 800000
#define NT 800000

typedef unsigned short u16;
typedef unsigned int u32;
typedef __attribute__((ext_vector_type(8))) short short8;
typedef __attribute__((ext_vector_type(4))) float f32x4;

__device__ __forceinline__ float silu_f(float x) { return x / (1.f + __expf(-x)); }
__device__ __forceinline__ float sigm_f(float x) { return 1.f / (1.f + __expf(-x)); }
__device__ __forceinline__ u16 f2b(float x) {
  u32 u = __float_as_uint(x);
  u32 r = u + 0x7fffu + ((u >> 16) & 1u);
  return (u16)(r >> 16);
}
__device__ __forceinline__ float b2f(u16 h) { return __uint_as_float(((u32)h) << 16); }
__device__ __forceinline__ u32 pk2(float a, float b) {
  return (u32)f2b(a) | ((u32)f2b(b) << 16);
}

// XOR-swizzled LDS elem offset for row-major [*][RW] u16 tiles (16B-chunk ^ (r&7)).
template <int RW>
__device__ __forceinline__ int lx(int r, int c) {
  return r * RW + ((((c >> 3) ^ (r & 7)) << 3) | (c & 7));
}

// ---------------- merged bf16 conversion + histograms (1 launch)
__global__ __launch_bounds__(256) void kcvt_hist(
    const float* __restrict__ erbf, u16* __restrict__ erbf_bf,
    const float* __restrict__ s, u16* __restrict__ s_bf,
    const int* __restrict__ tji, const int* __restrict__ edst,
    int* __restrict__ tcnt, int* __restrict__ ncnt) {
  int i = blockIdx.x * 256 + threadIdx.x;
  const int NCVT = (NE + NN) * 16;
  if (i < NCVT) {
    const float* in; u16* out; int j;
    if (i < NE * 16) { in = erbf; out = erbf_bf; j = i; }
    else { in = s; out = s_bf; j = i - NE * 16; }
    float4 v = ((const float4*)in)[j];
    uint2 p;
    p.x = pk2(v.x, v.y);
    p.y = pk2(v.z, v.w);
    ((uint2*)out)[j] = p;
  } else {
    int j = i - NCVT;
    if (j < NT) atomicAdd(&tcnt[tji[j]], 1);
    else {
      j -= NT;
      if (j < NE) atomicAdd(&ncnt[edst[j]], 1);
    }
  }
}

// ---------------- combined 2-range scans (proven)
__global__ __launch_bounds__(256) void kscan1b(
    const int* __restrict__ inA, int nA, int* __restrict__ outA, int* __restrict__ bsA, int BA,
    const int* __restrict__ inB, int nB, int* __restrict__ outB, int* __restrict__ bsB) {
  __shared__ int sh[256];
  const int* in; int n; int* out; int* bs; int blk;
  if ((int)blockIdx.x < BA) { in = inA; n = nA; out = outA; bs = bsA; blk = blockIdx.x; }
  else { in = inB; n = nB; out = outB; bs = bsB; blk = blockIdx.x - BA; }
  int tid = threadIdx.x;
  size_t base = (size_t)blk * 1024;
  int v[4];
  int acc = 0;
#pragma unroll
  for (int q = 0; q < 4; ++q) {
    size_t i = base + (size_t)tid * 4 + q;
    int x = (i < (size_t)n) ? in[i] : 0;
    v[q] = acc;
    acc += x;
  }
  sh[tid] = acc;
  __syncthreads();
  for (int off = 1; off < 256; off <<= 1) {
    int y = (tid >= off) ? sh[tid - off] : 0;
    __syncthreads();
    sh[tid] += y;
    __syncthreads();
  }
  int excl = (tid == 0) ? 0 : sh[tid - 1];
  if (tid == 255) bs[blk] = sh[255];
#pragma unroll
  for (int q = 0; q < 4; ++q) {
    size_t i = base + (size_t)tid * 4 + q;
    if (i < (size_t)n) out[i] = excl + v[q];
  }
}

__global__ __launch_bounds__(1024) void kscan2b(int* __restrict__ bsA, int nbA,
                                                int* __restrict__ bsB, int nbB) {
  __shared__ int sh[1024];
  int* bs = (blockIdx.x == 0) ? bsA : bsB;
  int nb = (blockIdx.x == 0) ? nbA : nbB;
  int tid = threadIdx.x;
  sh[tid] = (tid < nb) ? bs[tid] : 0;
  __syncthreads();
  for (int off = 1; off < 1024; off <<= 1) {
    int y = (tid >= off) ? sh[tid - off] : 0;
    __syncthreads();
    sh[tid] += y;
    __syncthreads();
  }
  if (tid < nb) bs[tid] = (tid == 0) ? 0 : sh[tid - 1];
}

__global__ __launch_bounds__(256) void kscan3b(
    int* __restrict__ outA, const int* __restrict__ bsA, int nA, int totalA,
    int* __restrict__ outB, const int* __restrict__ bsB, int nB, int totalB) {
  int i = blockIdx.x * 256 + threadIdx.x;
  if (i <= nA) {
    if (i < nA) outA[i] += bsA[i >> 10];
    else outA[nA] = totalA;
  } else {
    int j = i - (nA + 1);
    if (j < nB) outB[j] += bsB[j >> 10];
    else if (j == nB) outB[nB] = totalB;
  }
}

// ---------------- combined prep: triplet scatter + edge scatter + weight pack
__global__ __launch_bounds__(256) void kprep_all(
    const int* __restrict__ tji, const int* __restrict__ toff, int* __restrict__ tcnt,
    int* __restrict__ tids, const float* __restrict__ afeat, u16* __restrict__ afeat_s,
    const int* __restrict__ edst, const int* __restrict__ noff, int* __restrict__ ncnt,
    int* __restrict__ eslot, const float* __restrict__ dir, float* __restrict__ dir_s,
    const float* __restrict__ Wt1, const float* __restrict__ Wt2,
    const float* __restrict__ Wm1, const float* __restrict__ Wm2,
    const float* __restrict__ Wu1, const float* __restrict__ Wu2,
    const float* __restrict__ Wg1, const float* __restrict__ Wg2,
    u16* __restrict__ Pt1, u16* __restrict__ Pt2,
    u16* __restrict__ Pm1, u16* __restrict__ Pm2,
    u16* __restrict__ Pu1, u16* __restrict__ Pu2,
    u16* __restrict__ Pg1, u16* __restrict__ Pg2) {
  int i = blockIdx.x * 256 + threadIdx.x;
  if (i < NT) {
    int k = tji[i];
    int slot = toff[k] + (atomicSub(&tcnt[k], 1) - 1);
    tids[slot] = i;
    const float4* src = (const float4*)(afeat + (size_t)i * 16);
    uint2* dst = (uint2*)(afeat_s + (size_t)slot * 16);
#pragma unroll
    for (int q = 0; q < 4; ++q) {
      float4 v = src[q];
      uint2 p;
      p.x = pk2(v.x, v.y);
      p.y = pk2(v.z, v.w);
      dst[q] = p;
    }
  } else if (i < NT + NE) {
    int j = i - NT;
    int k = edst[j];
    int slot = noff[k] + (atomicSub(&ncnt[k], 1) - 1);
    eslot[j] = slot;
    dir_s[(size_t)slot * 3 + 0] = dir[(size_t)j * 3 + 0];
    dir_s[(size_t)slot * 3 + 1] = dir[(size_t)j * 3 + 1];
    dir_s[(size_t)slot * 3 + 2] = dir[(size_t)j * 3 + 2];
  } else {
    int g = i - NT - NE;
    int f = g >> 6, l = g & 63;
    const float* W; u16* out; int K, N, fl;
    if (f < 20)       { W = Wt1; out = Pt1; K = 144; N = 64;  fl = f; }
    else if (f < 28)  { W = Wt2; out = Pt2; K = 64;  N = 64;  fl = f - 20; }
    else if (f < 60)  { W = Wm1; out = Pm1; K = 256; N = 64;  fl = f - 28; }
    else if (f < 76)  { W = Wm2; out = Pm2; K = 64;  N = 128; fl = f - 60; }
    else if (f < 100) { W = Wu1; out = Pu1; K = 192; N = 64;  fl = f - 76; }
    else if (f < 108) { W = Wu2; out = Pu2; K = 64;  N = 64;  fl = f - 100; }
    else if (f < 132) { W = Wg1; out = Pg1; K = 192; N = 64;  fl = f - 108; }
    else if (f < 140) { W = Wg2; out = Pg2; K = 64;  N = 64;  fl = f - 132; }
    else return;
    int nt = fl % (N / 16);
    int kt = fl / (N / 16);
    int k0 = kt * 32 + (l >> 4) * 8;
    int n = nt * 16 + (l & 15);
    u16 vals[8];
#pragma unroll
    for (int j = 0; j < 8; ++j) {
      int kk = k0 + j;
      vals[j] = (kk < K) ? f2b(W[(size_t)kk * N + n]) : (u16)0;
    }
    uint4* dst = (uint4*)(out + (size_t)fl * 512 + l * 8);
    uint4 p;
    p.x = (u32)vals[0] | ((u32)vals[1] << 16);
    p.y = (u32)vals[2] | ((u32)vals[3] << 16);
    p.z = (u32)vals[4] | ((u32)vals[5] << 16);
    p.w = (u32)vals[6] | ((u32)vals[7] << 16);
    *dst = p;
  }
}

// ---------------- Kernel T (MFMA): triplet MLP in slot order; Hs overlaid in Xs -> 24KB LDS
__global__ __launch_bounds__(256) void ktrip_mfma(
    const int* __restrict__ tkj, const int* __restrict__ tji,
    const u16* __restrict__ erbf_bf, const u16* __restrict__ afeat_s,
    const int* __restrict__ tids,
    const u16* __restrict__ Wp1, const float* __restrict__ b1,
    const u16* __restrict__ Wp2, const float* __restrict__ b2,
    u16* __restrict__ tmsg_s) {
  __shared__ __align__(16) u16 Xs[64 * 192];          // 24KB total
  u16* Hs = Xs + 64 * 128;                            // overlay: bytes 16384..24575
  const int tid = threadIdx.x;
  const int l = tid & 63;
  const int w = tid >> 6;
  const int st0 = blockIdx.x * 64;

#pragma unroll
  for (int it = 0; it < 4; ++it) {
    int idx = it * 256 + tid;
    int sel = idx >> 9, r = (idx >> 3) & 63, ch = idx & 7;
    int t = tids[st0 + r];
    int node = sel ? tji[t] : tkj[t];
    uint4 vv = *(const uint4*)&erbf_bf[(size_t)node * 64 + ch * 8];
    *(uint4*)&Xs[lx<192>(r, sel * 64 + ch * 8)] = vv;
  }
  {
    int r = tid >> 2, c = (tid & 3) * 4;
    uint2 p2 = *(const uint2*)&afeat_s[(size_t)(st0 + r) * 16 + c];
    *(uint2*)&Xs[lx<192>(r, 128 + c)] = p2;
  }
#pragma unroll
  for (int i = 0; i < 2; ++i) {
    int idx = i * 256 + tid;
    int r = idx >> 3, c = 144 + (idx & 7) * 2;
    *(u32*)&Xs[lx<192>(r, c)] = 0;
  }
  __syncthreads();

  f32x4 acc1[4];
  {
    float bias = b1[w * 16 + (l & 15)];
#pragma unroll
    for (int mt = 0; mt < 4; ++mt) acc1[mt] = (f32x4){bias, bias, bias, bias};
    for (int ks = 0; ks < 5; ++ks) {
      short8 bf = *(const short8*)(Wp1 + ((size_t)(ks * 4 + w) * 64 + l) * 8);
#pragma unroll
      for (int mt = 0; mt < 4; ++mt) {
        short8 af = *(const short8*)&Xs[lx<192>(mt * 16 + (l & 15), ks * 32 + ((l >> 4) << 3))];
        acc1[mt] = __builtin_amdgcn_mfma_f32_16x16x32_bf16(af, bf, acc1[mt], 0, 0, 0);
      }
    }
  }
  __syncthreads();  // all Xs reads done before Hs overlay write
#pragma unroll
  for (int mt = 0; mt < 4; ++mt)
#pragma unroll
    for (int q = 0; q < 4; ++q) {
      int r = mt * 16 + (l >> 4) * 4 + q;
      Hs[lx<64>(r, w * 16 + (l & 15))] = f2b(silu_f(acc1[mt][q]));
    }
  __syncthreads();

  f32x4 acc2[4];
  {
    float bias = b2[w * 16 + (l & 15)];
#pragma unroll
    for (int mt = 0; mt < 4; ++mt) acc2[mt] = (f32x4){bias, bias, bias, bias};
    for (int ks = 0; ks < 2; ++ks) {
      short8 bf = *(const short8*)(Wp2 + ((size_t)(ks * 4 + w) * 64 + l) * 8);
#pragma unroll
      for (int mt = 0; mt < 4; ++mt) {
        short8 af = *(const short8*)&Hs[lx<64>(mt * 16 + (l & 15), ks * 32 + ((l >> 4) << 3))];
        acc2[mt] = __builtin_amdgcn_mfma_f32_16x16x32_bf16(af, bf, acc2[mt], 0, 0, 0);
      }
    }
  }
  __syncthreads();
#pragma unroll
  for (int mt = 0; mt < 4; ++mt)
#pragma unroll
    for (int q = 0; q < 4; ++q) {
      int r = mt * 16 + (l >> 4) * 4 + q;
      Xs[lx<64>(r, w * 16 + (l & 15))] = f2b(acc2[mt][q]);   // bytes 0..8191, no Hs overlap
    }
  __syncthreads();
  for (int i = 0; i < 2; ++i) {
    int idx = i * 256 + tid;
    int r = idx >> 3, c0 = (idx & 7) << 3;
    uint4 val = *(const uint4*)&Xs[lx<64>(r, c0)];
    *(uint4*)(tmsg_s + (size_t)(st0 + r) * 64 + c0) = val;
  }
}

// ---------------- Kernel M (MFMA): natural edge order -> msg_s[eslot]; Hs overlaid -> 32KB LDS
__global__ __launch_bounds__(256) void kmsg_mfma(
    const int* __restrict__ eidx, const u16* __restrict__ s_bf,
    const u16* __restrict__ erbf_bf,
    const int* __restrict__ toff, const u16* __restrict__ tmsg_s,
    const int* __restrict__ eslot,
    const u16* __restrict__ Wp1, const float* __restrict__ b1,
    const u16* __restrict__ Wp2, const float* __restrict__ b2,
    u16* __restrict__ msg_s) {
  __shared__ __align__(16) u16 Xs[64 * 256];          // 32KB total
  u16* Hs = Xs + 64 * 192;                            // overlay: bytes 24576..32767
  const int tid = threadIdx.x;
  const int l = tid & 63;
  const int w = tid >> 6;
  const int e0 = blockIdx.x * 64;

  // erbf stream cols 128..191
#pragma unroll
  for (int i = 0; i < 2; ++i) {
    int idx = i * 256 + tid;
    int r = idx >> 3, c0 = (idx & 7) << 3;
    uint4 vv = *(const uint4*)&erbf_bf[(size_t)(e0 + r) * 64 + c0];
    *(uint4*)&Xs[lx<256>(r, 128 + c0)] = vv;
  }
  // s[src], s[dst] gathers
#pragma unroll
  for (int it = 0; it < 4; ++it) {
    int idx = it * 256 + tid;
    int sel = idx >> 9, r = (idx >> 3) & 63, ch = idx & 7;
    int node = eidx[sel * NE + e0 + r];
    uint4 vv = *(const uint4*)&s_bf[(size_t)node * 64 + ch * 8];
    *(uint4*)&Xs[lx<256>(r, sel * 64 + ch * 8)] = vv;
  }
  // aagg contiguous CSR sum
#pragma unroll
  for (int it = 0; it < 2; ++it) {
    int idx = it * 256 + tid;
    int r = idx >> 3, ch = idx & 7;
    int e = e0 + r;
    int r0 = toff[e], r1 = toff[e + 1];
    float a[8];
#pragma unroll
    for (int j = 0; j < 8; ++j) a[j] = 0.f;
    for (int ri = r0; ri < r1; ++ri) {
      uint4 pk = *(const uint4*)&tmsg_s[(size_t)ri * 64 + ch * 8];
      a[0] += b2f((u16)(pk.x & 0xffff)); a[1] += b2f((u16)(pk.x >> 16));
      a[2] += b2f((u16)(pk.y & 0xffff)); a[3] += b2f((u16)(pk.y >> 16));
      a[4] += b2f((u16)(pk.z & 0xffff)); a[5] += b2f((u16)(pk.z >> 16));
      a[6] += b2f((u16)(pk.w & 0xffff)); a[7] += b2f((u16)(pk.w >> 16));
    }
    uint4 p;
    p.x = pk2(a[0], a[1]);
    p.y = pk2(a[2], a[3]);
    p.z = pk2(a[4], a[5]);
    p.w = pk2(a[6], a[7]);
    *(uint4*)&Xs[lx<256>(r, 192 + ch * 8)] = p;
  }
  __syncthreads();

  f32x4 acc1[4];
  {
    float bias = b1[w * 16 + (l & 15)];
#pragma unroll
    for (int mt = 0; mt < 4; ++mt) acc1[mt] = (f32x4){bias, bias, bias, bias};
    for (int ks = 0; ks < 8; ++ks) {
      short8 bf = *(const short8*)(Wp1 + ((size_t)(ks * 4 + w) * 64 + l) * 8);
#pragma unroll
      for (int mt = 0; mt < 4; ++mt) {
        short8 af = *(const short8*)&Xs[lx<256>(mt * 16 + (l & 15), ks * 32 + ((l >> 4) << 3))];
        acc1[mt] = __builtin_amdgcn_mfma_f32_16x16x32_bf16(af, bf, acc1[mt], 0, 0, 0);
      }
    }
  }
  __syncthreads();  // all Xs reads done before Hs overlay write
#pragma unroll
  for (int mt = 0; mt < 4; ++mt)
#pragma unroll
    for (int q = 0; q < 4; ++q) {
      int r = mt * 16 + (l >> 4) * 4 + q;
      Hs[lx<64>(r, w * 16 + (l & 15))] = f2b(silu_f(acc1[mt][q]));
    }
  __syncthreads();

  f32x4 acc2[2][4];
#pragma unroll
  for (int pp = 0; pp < 2; ++pp) {
    int nt = w * 2 + pp;
    float bias = b2[nt * 16 + (l & 15)];
#pragma unroll
    for (int mt = 0; mt < 4; ++mt) acc2[pp][mt] = (f32x4){bias, bias, bias, bias};
    for (int ks = 0; ks < 2; ++ks) {
      short8 bf = *(const short8*)(Wp2 + ((size_t)(ks * 8 + nt) * 64 + l) * 8);
#pragma unroll
      for (int mt = 0; mt < 4; ++mt) {
        short8 af = *(const short8*)&Hs[lx<64>(mt * 16 + (l & 15), ks * 32 + ((l >> 4) << 3))];
        acc2[pp][mt] = __builtin_amdgcn_mfma_f32_16x16x32_bf16(af, bf, acc2[pp][mt], 0, 0, 0);
      }
    }
  }
  __syncthreads();
#pragma unroll
  for (int pp = 0; pp < 2; ++pp)
#pragma unroll
    for (int mt = 0; mt < 4; ++mt)
#pragma unroll
      for (int q = 0; q < 4; ++q) {
        int r = mt * 16 + (l >> 4) * 4 + q;
        Xs[lx<128>(r, (w * 2 + pp) * 16 + (l & 15))] = f2b(acc2[pp][mt][q]);  // bytes 0..16383
      }
  __syncthreads();
  for (int i = 0; i < 4; ++i) {
    int idx = i * 256 + tid;
    int r = idx >> 4, c0 = (idx & 15) << 3;
    int slot = eslot[e0 + r];
    uint4 val = *(const uint4*)&Xs[lx<128>(r, c0)];
    *(uint4*)(msg_s + (size_t)slot * 128 + c0) = val;
  }
}

// ---------------- Kernel A (proven): streaming CSR reduction, 4 rows/iter, uint4 loads
__global__ __launch_bounds__(256) void kagg(
    const int* __restrict__ noff, const u16* __restrict__ msg_s,
    const float* __restrict__ dir_s,
    u16* __restrict__ aggs_bf, float* __restrict__ aggv) {
  const int lane = threadIdx.x & 63;
  const int wv = threadIdx.x >> 6;
  const int n = blockIdx.x * 4 + wv;
  if (n >= NN) return;
  const int r0 = noff[n], r1 = noff[n + 1];
  const int lrow = lane >> 4, lcol = lane & 15;
  const bool is_ms = (lcol < 8);

  float a[8];
  float v0[8], v1[8], v2[8];
#pragma unroll
  for (int j = 0; j < 8; ++j) { a[j] = 0.f; v0[j] = 0.f; v1[j] = 0.f; v2[j] = 0.f; }

  for (int r4 = r0; r4 < r1; r4 += 4) {
    int r = r4 + lrow;
    if (r < r1) {
      uint4 pk = *(const uint4*)&msg_s[(size_t)r * 128 + lcol * 8];
      float x[8];
      x[0] = b2f((u16)(pk.x & 0xffff)); x[1] = b2f((u16)(pk.x >> 16));
      x[2] = b2f((u16)(pk.y & 0xffff)); x[3] = b2f((u16)(pk.y >> 16));
      x[4] = b2f((u16)(pk.z & 0xffff)); x[5] = b2f((u16)(pk.z >> 16));
      x[6] = b2f((u16)(pk.w & 0xffff)); x[7] = b2f((u16)(pk.w >> 16));
      if (is_ms) {
#pragma unroll
        for (int j = 0; j < 8; ++j) a[j] += x[j];
      } else {
        float dx = dir_s[(size_t)r * 3 + 0];
        float dy = dir_s[(size_t)r * 3 + 1];
        float dz = dir_s[(size_t)r * 3 + 2];
#pragma unroll
        for (int j = 0; j < 8; ++j) {
          v0[j] += x[j] * dx; v1[j] += x[j] * dy; v2[j] += x[j] * dz;
        }
      }
    }
  }
#pragma unroll
  for (int j = 0; j < 8; ++j) {
    a[j] += __shfl_xor(a[j], 16);  a[j] += __shfl_xor(a[j], 32);
    v0[j] += __shfl_xor(v0[j], 16); v0[j] += __shfl_xor(v0[j], 32);
    v1[j] += __shfl_xor(v1[j], 16); v1[j] += __shfl_xor(v1[j], 32);
    v2[j] += __shfl_xor(v2[j], 16); v2[j] += __shfl_xor(v2[j], 32);
  }
  if (lrow == 0) {
    if (is_ms) {
      uint4 p;
      p.x = pk2(a[0], a[1]);
      p.y = pk2(a[2], a[3]);
      p.z = pk2(a[4], a[5]);
      p.w = pk2(a[6], a[7]);
      *(uint4*)&aggs_bf[(size_t)n * 64 + lcol * 8] = p;
    } else {
      int c0 = (lcol - 8) * 8;
      float* av = aggv + (size_t)n * 192 + (size_t)c0 * 3;
      float4 o0 = {v0[0], v1[0], v2[0], v0[1]};
      float4 o1 = {v1[1], v2[1], v0[2], v1[2]};
      float4 o2 = {v2[2], v0[3], v1[3], v2[3]};
      float4 o3 = {v0[4], v1[4], v2[4], v0[5]};
      float4 o4 = {v1[5], v2[5], v0[6], v1[6]};
      float4 o5 = {v2[6], v0[7], v1[7], v2[7]};
      float4* av4 = (float4*)av;
      av4[0] = o0; av4[1] = o1; av4[2] = o2; av4[3] = o3; av4[4] = o4; av4[5] = o5;
    }
  }
}

// ---------------- Kernel N (MFMA, proven)
__global__ __launch_bounds__(256) void knode_mfma(
    const u16* __restrict__ s_bf, const float* __restrict__ v,
    const u16* __restrict__ aggs_bf, const float* __restrict__ aggv,
    const u16* __restrict__ WpU1, const float* __restrict__ bU1,
    const u16* __restrict__ WpU2, const float* __restrict__ bU2,
    const u16* __restrict__ WpG1, const float* __restrict__ bG1,
    const u16* __restrict__ WpG2, const float* __restrict__ bG2,
    const float* __restrict__ lng, const float* __restrict__ lnb,
    float* __restrict__ outs, float* __restrict__ outv) {
  __shared__ __align__(16) char smem[64 * 192 * 2 + 2 * 64 * 64 * 2];  // 40KB
  u16* Xs = (u16*)smem;
  u16* Hu = (u16*)(smem + 64 * 192 * 2);
  u16* Hg = Hu + 64 * 64;
  float* Fs = (float*)smem;

  const int tid = threadIdx.x;
  const int l = tid & 63;
  const int w = tid >> 6;
  const int n0 = blockIdx.x * 64;

  for (int i = 0; i < 2; ++i) {
    int idx = i * 256 + tid;
    int r = idx >> 3, c0 = (idx & 7) << 3;
    int nr = n0 + r; if (nr >= NN) nr = NN - 1;
    uint4 a = *(const uint4*)&s_bf[(size_t)nr * 64 + c0];
    *(uint4*)&Xs[lx<192>(r, c0)] = a;
    uint4 b = *(const uint4*)&aggs_bf[(size_t)nr * 64 + c0];
    *(uint4*)&Xs[lx<192>(r, 64 + c0)] = b;
  }
  for (int it = 0; it < 16; ++it) {
    int idx = it * 256 + tid;
    int r = idx >> 6, c = idx & 63;
    int nr = n0 + r; if (nr >= NN) nr = NN - 1;
    const float* vp = v + (size_t)nr * 192 + c * 3;
    float x = vp[0], y = vp[1], z = vp[2];
    Xs[lx<192>(r, 128 + c)] = f2b(sqrtf(x * x + y * y + z * z));
  }
  __syncthreads();

  f32x4 au[4], ag[4];
  {
    float biu = bU1[w * 16 + (l & 15)], big = bG1[w * 16 + (l & 15)];
#pragma unroll
    for (int mt = 0; mt < 4; ++mt) {
      au[mt] = (f32x4){biu, biu, biu, biu};
      ag[mt] = (f32x4){big, big, big, big};
    }
    for (int ks = 0; ks < 6; ++ks) {
      short8 bu = *(const short8*)(WpU1 + ((size_t)(ks * 4 + w) * 64 + l) * 8);
      short8 bg = *(const short8*)(WpG1 + ((size_t)(ks * 4 + w) * 64 + l) * 8);
#pragma unroll
      for (int mt = 0; mt < 4; ++mt) {
        short8 af = *(const short8*)&Xs[lx<192>(mt * 16 + (l & 15), ks * 32 + ((l >> 4) << 3))];
        au[mt] = __builtin_amdgcn_mfma_f32_16x16x32_bf16(af, bu, au[mt], 0, 0, 0);
        ag[mt] = __builtin_amdgcn_mfma_f32_16x16x32_bf16(af, bg, ag[mt], 0, 0, 0);
      }
    }
  }
#pragma unroll
  for (int mt = 0; mt < 4; ++mt)
#pragma unroll
    for (int q = 0; q < 4; ++q) {
      int r = mt * 16 + (l >> 4) * 4 + q;
      Hu[lx<64>(r, w * 16 + (l & 15))] = f2b(silu_f(au[mt][q]));
      Hg[lx<64>(r, w * 16 + (l & 15))] = f2b(silu_f(ag[mt][q]));
    }
  __syncthreads();

  f32x4 ou[4], og[4];
  {
    float biu = bU2[w * 16 + (l & 15)], big = bG2[w * 16 + (l & 15)];
#pragma unroll
    for (int mt = 0; mt < 4; ++mt) {
      ou[mt] = (f32x4){biu, biu, biu, biu};
      og[mt] = (f32x4){big, big, big, big};
    }
    for (int ks = 0; ks < 2; ++ks) {
      short8 bu = *(const short8*)(WpU2 + ((size_t)(ks * 4 + w) * 64 + l) * 8);
      short8 bg = *(const short8*)(WpG2 + ((size_t)(ks * 4 + w) * 64 + l) * 8);
#pragma unroll
      for (int mt = 0; mt < 4; ++mt) {
        short8 afu = *(const short8*)&Hu[lx<64>(mt * 16 + (l & 15), ks * 32 + ((l >> 4) << 3))];
        ou[mt] = __builtin_amdgcn_mfma_f32_16x16x32_bf16(afu, bu, ou[mt], 0, 0, 0);
        short8 afg = *(const short8*)&Hg[lx<64>(mt * 16 + (l & 15), ks * 32 + ((l >> 4) << 3))];
        og[mt] = __builtin_amdgcn_mfma_f32_16x16x32_bf16(afg, bg, og[mt], 0, 0, 0);
      }
    }
  }
#pragma unroll
  for (int mt = 0; mt < 4; ++mt)
#pragma unroll
    for (int q = 0; q < 4; ++q) {
      int r = mt * 16 + (l >> 4) * 4 + q;
      ou[mt][q] += b2f(Xs[lx<192>(r, w * 16 + (l & 15))]);
    }
  __syncthreads();

#pragma unroll
  for (int mt = 0; mt < 4; ++mt)
#pragma unroll
    for (int q = 0; q < 4; ++q) {
      int r = mt * 16 + (l >> 4) * 4 + q;
      Fs[r * 68 + w * 16 + (l & 15)] = ou[mt][q];
    }
  __syncthreads();
  {
    int r = tid >> 2, c0 = (tid & 3) * 16;
    float xv[16];
#pragma unroll
    for (int j4 = 0; j4 < 4; ++j4) {
      float4 t = *(const float4*)&Fs[r * 68 + c0 + j4 * 4];
      xv[j4 * 4 + 0] = t.x; xv[j4 * 4 + 1] = t.y;
      xv[j4 * 4 + 2] = t.z; xv[j4 * 4 + 3] = t.w;
    }
    float sm = 0.f, sq = 0.f;
#pragma unroll
    for (int j = 0; j < 16; ++j) { sm += xv[j]; sq += xv[j] * xv[j]; }
    sm += __shfl_xor(sm, 1); sq += __shfl_xor(sq, 1);
    sm += __shfl_xor(sm, 2); sq += __shfl_xor(sq, 2);
    float mu = sm * (1.f / 64.f);
    float var = sq * (1.f / 64.f) - mu * mu;
    float rstd = rsqrtf(var + 1e-5f);
    if (n0 + r < NN) {
      float* op = outs + (size_t)(n0 + r) * 64 + c0;
#pragma unroll
      for (int j4 = 0; j4 < 4; ++j4) {
        float4 o;
        float y0 = (xv[j4 * 4 + 0] - mu) * rstd * lng[c0 + j4 * 4 + 0] + lnb[c0 + j4 * 4 + 0];
        float y1 = (xv[j4 * 4 + 1] - mu) * rstd * lng[c0 + j4 * 4 + 1] + lnb[c0 + j4 * 4 + 1];
        float y2 = (xv[j4 * 4 + 2] - mu) * rstd * lng[c0 + j4 * 4 + 2] + lnb[c0 + j4 * 4 + 2];
        float y3 = (xv[j4 * 4 + 3] - mu) * rstd * lng[c0 + j4 * 4 + 3] + lnb[c0 + j4 * 4 + 3];
        o.x = silu_f(y0); o.y = silu_f(y1); o.z = silu_f(y2); o.w = silu_f(y3);
        *(float4*)(op + j4 * 4) = o;
      }
    }
  }
  __syncthreads();

#pragma unroll
  for (int mt = 0; mt < 4; ++mt)
#pragma unroll
    for (int q = 0; q < 4; ++q) {
      int r = mt * 16 + (l >> 4) * 4 + q;
      Fs[r * 68 + w * 16 + (l & 15)] = og[mt][q];
    }
  __syncthreads();
  {
    int r = tid >> 2, c0 = (tid & 3) * 16;
    int nr = n0 + r;
    if (nr < NN) {
      float gate[16];
#pragma unroll
      for (int j = 0; j < 16; ++j) gate[j] = sigm_f(Fs[r * 68 + c0 + j]);
      const float4* vp = (const float4*)(v + (size_t)nr * 192 + c0 * 3);
      const float4* ap = (const float4*)(aggv + (size_t)nr * 192 + c0 * 3);
      float4* op = (float4*)(outv + (size_t)nr * 192 + c0 * 3);
#pragma unroll
      for (int j4 = 0; j4 < 12; ++j4) {
        float4 vv = vp[j4], av = ap[j4], o;
        o.x = vv.x + gate[(j4 * 4 + 0) / 3] * av.x;
        o.y = vv.y + gate[(j4 * 4 + 1) / 3] * av.y;
        o.z = vv.z + gate[(j4 * 4 + 2) / 3] * av.z;
        o.w = vv.w + gate[(j4 * 4 + 3) / 3] * av.w;
        op[j4] = o;
      }
    }
  }
}

extern "C" void kernel_launch(void* const* d_in, const int* in_sizes, int n_in,
                              void* d_out, int out_size, void* d_ws, size_t ws_size,
                              hipStream_t stream) {
  const float* s     = (const float*)d_in[0];
  const float* v     = (const float*)d_in[1];
  const int*   eidx  = (const int*)d_in[2];
  const float* erbf  = (const float*)d_in[3];
  const float* edir  = (const float*)d_in[4];
  const int*   tkj   = (const int*)d_in[5];
  const int*   tji   = (const int*)d_in[6];
  const float* afeat = (const float*)d_in[7];
  const float* W_t1  = (const float*)d_in[8];
  const float* b_t1  = (const float*)d_in[9];
  const float* W_t2  = (const float*)d_in[10];
  const float* b_t2  = (const float*)d_in[11];
  const float* W_m1  = (const float*)d_in[12];
  const float* b_m1  = (const float*)d_in[13];
  const float* W_m2  = (const float*)d_in[14];
  const float* b_m2  = (const float*)d_in[15];
  const float* W_u1  = (const float*)d_in[16];
  const float* b_u1  = (const float*)d_in[17];
  const float* W_u2  = (const float*)d_in[18];
  const float* b_u2  = (const float*)d_in[19];
  const float* W_g1  = (const float*)d_in[20];
  const float* b_g1  = (const float*)d_in[21];
  const float* W_g2  = (const float*)d_in[22];
  const float* b_g2  = (const float*)d_in[23];
  const float* ln_g  = (const float*)d_in[24];
  const float* ln_b  = (const float*)d_in[25];

  char* w = (char*)d_ws;
  auto alloc = [&](size_t bytes) -> char* {
    char* p = w;
    w += (bytes + 255) & ~(size_t)255;
    return p;
  };
  int* tcnt  = (int*)alloc((size_t)NE * 4);
  int* ncnt  = (int*)alloc((size_t)NN * 4);
  size_t zspan = (size_t)((char*)(ncnt + NN) - (char*)tcnt);
  int* toff  = (int*)alloc((size_t)(NE + 1) * 4);
  int* noff  = (int*)alloc((size_t)(NN + 1) * 4);
  int* tids  = (int*)alloc((size_t)NT * 4);
  int* eslot = (int*)alloc((size_t)NE * 4);
  int* bsum  = (int*)alloc(2048 * 4);
  float* dir_s = (float*)alloc((size_t)NE * 3 * 4);
  u16* msg_s  = (u16*)alloc((size_t)NE * 128 * 2);       // 204.8 MB
  u16* tmsg_s = (u16*)alloc((size_t)NT * 64 * 2);        // 102.4 MB
  u16* erbf_bf = (u16*)alloc((size_t)NE * 64 * 2);       // 102.4 MB
  u16* s_bf    = (u16*)alloc((size_t)NN * 64 * 2);       // 6.4 MB
  u16* Wp_t1 = (u16*)alloc((size_t)5 * 4 * 512 * 2);
  u16* Wp_t2 = (u16*)alloc((size_t)2 * 4 * 512 * 2);
  u16* Wp_m1 = (u16*)alloc((size_t)8 * 4 * 512 * 2);
  u16* Wp_m2 = (u16*)alloc((size_t)2 * 8 * 512 * 2);
  u16* Wp_u1 = (u16*)alloc((size_t)6 * 4 * 512 * 2);
  u16* Wp_u2 = (u16*)alloc((size_t)2 * 4 * 512 * 2);
  u16* Wp_g1 = (u16*)alloc((size_t)6 * 4 * 512 * 2);
  u16* Wp_g2 = (u16*)alloc((size_t)2 * 4 * 512 * 2);
  u16* afeat_s = msg_s;            // alias: read only by ktrip; msg_s written later by kmsg
  float* aggv = (float*)tmsg_s;    // alias: tmsg_s dead after kmsg
  u16* aggs_bf = tmsg_s + (size_t)NN * 384;

  hipMemsetAsync(tcnt, 0, zspan, stream);

  kcvt_hist<<<((NE + NN) * 16 + NT + NE + 255) / 256, 256, 0, stream>>>(
      erbf, erbf_bf, s, s_bf, tji, eidx + NE, tcnt, ncnt);

  const int Bt = (NE + 1023) / 1024, Bn = (NN + 1023) / 1024;
  kscan1b<<<Bt + Bn, 256, 0, stream>>>(tcnt, NE, toff, bsum, Bt, ncnt, NN, noff, bsum + 1024);
  kscan2b<<<2, 1024, 0, stream>>>(bsum, Bt, bsum + 1024, Bn);
  kscan3b<<<(NE + 1 + NN + 1 + 255) / 256, 256, 0, stream>>>(toff, bsum, NE, NT,
                                                             noff, bsum + 1024, NN, NE);

  kprep_all<<<(NT + NE + 140 * 64 + 255) / 256, 256, 0, stream>>>(
      tji, toff, tcnt, tids, afeat, afeat_s,
      eidx + NE, noff, ncnt, eslot, edir, dir_s,
      W_t1, W_t2, W_m1, W_m2, W_u1, W_u2, W_g1, W_g2,
      Wp_t1, Wp_t2, Wp_m1, Wp_m2, Wp_u1, Wp_u2, Wp_g1, Wp_g2);

  ktrip_mfma<<<NT / 64, 256, 0, stream>>>(tkj, tji, erbf_bf, afeat_s, tids,
                                          Wp_t1, b_t1, Wp_t2, b_t2, tmsg_s);
  kmsg_mfma<<<NE / 64, 256, 0, stream>>>(eidx, s_bf, erbf_bf, toff, tmsg_s, eslot,
                                         Wp_m1, b_m1, Wp_m2, b_m2, msg_s);
  kagg<<<(NN + 3) / 4, 256, 0, stream>>>(noff, msg_s, dir_s, aggs_bf, aggv);

  float* out_s = (float*)d_out;
  float* out_v = out_s + (size_t)NN * 64;
  knode_mfma<<<(NN + 63) / 64, 256, 0, stream>>>(s_bf, v, aggs_bf, aggv,
                                                 Wp_u1, b_u1, Wp_u2, b_u2,
                                                 Wp_g1, b_g1, Wp_g2, b_g2,
                                                 ln_g, ln_b, out_s, out_v);
}

// Round 14
// 608.584 us; speedup vs baseline: 1.0187x; 1.0187x over previous
//
#include <hip/hip_runtime.h>
#include <cstdint>
#include <cstddef>

#define NN 50000
#define NE 800000
#define NT 800000

typedef unsigned short u16;
typedef unsigned int u32;
typedef __attribute__((ext_vector_type(8))) short short8;
typedef __attribute__((ext_vector_type(4))) float f32x4;

__device__ __forceinline__ float silu_f(float x) { return x / (1.f + __expf(-x)); }
__device__ __forceinline__ float sigm_f(float x) { return 1.f / (1.f + __expf(-x)); }
__device__ __forceinline__ u16 f2b(float x) {
  u32 u = __float_as_uint(x);
  u32 r = u + 0x7fffu + ((u >> 16) & 1u);
  return (u16)(r >> 16);
}
__device__ __forceinline__ float b2f(u16 h) { return __uint_as_float(((u32)h) << 16); }
__device__ __forceinline__ u32 pk2(float a, float b) {
  return (u32)f2b(a) | ((u32)f2b(b) << 16);
}

// XOR-swizzled LDS elem offset for row-major [*][RW] u16 tiles (16B-chunk ^ (r&7)).
template <int RW>
__device__ __forceinline__ int lx(int r, int c) {
  return r * RW + ((((c >> 3) ^ (r & 7)) << 3) | (c & 7));
}

// async HBM -> LDS, 16B per lane, dest = lds + lane*16 (wave-uniform base)
__device__ __forceinline__ void gload16(const void* g, void* l) {
  __builtin_amdgcn_global_load_lds((const __attribute__((address_space(1))) void*)g,
                                   (__attribute__((address_space(3))) void*)l, 16, 0, 0);
}

// ---------------- merged bf16 conversion + histograms (1 launch)
__global__ __launch_bounds__(256) void kcvt_hist(
    const float* __restrict__ erbf, u16* __restrict__ erbf_bf,
    const float* __restrict__ s, u16* __restrict__ s_bf,
    const int* __restrict__ tji, const int* __restrict__ edst,
    int* __restrict__ tcnt, int* __restrict__ ncnt) {
  int i = blockIdx.x * 256 + threadIdx.x;
  const int NCVT = (NE + NN) * 16;
  if (i < NCVT) {
    const float* in; u16* out; int j;
    if (i < NE * 16) { in = erbf; out = erbf_bf; j = i; }
    else { in = s; out = s_bf; j = i - NE * 16; }
    float4 v = ((const float4*)in)[j];
    uint2 p;
    p.x = pk2(v.x, v.y);
    p.y = pk2(v.z, v.w);
    ((uint2*)out)[j] = p;
  } else {
    int j = i - NCVT;
    if (j < NT) atomicAdd(&tcnt[tji[j]], 1);
    else {
      j -= NT;
      if (j < NE) atomicAdd(&ncnt[edst[j]], 1);
    }
  }
}

// ---------------- combined 2-range scans (proven)
__global__ __launch_bounds__(256) void kscan1b(
    const int* __restrict__ inA, int nA, int* __restrict__ outA, int* __restrict__ bsA, int BA,
    const int* __restrict__ inB, int nB, int* __restrict__ outB, int* __restrict__ bsB) {
  __shared__ int sh[256];
  const int* in; int n; int* out; int* bs; int blk;
  if ((int)blockIdx.x < BA) { in = inA; n = nA; out = outA; bs = bsA; blk = blockIdx.x; }
  else { in = inB; n = nB; out = outB; bs = bsB; blk = blockIdx.x - BA; }
  int tid = threadIdx.x;
  size_t base = (size_t)blk * 1024;
  int v[4];
  int acc = 0;
#pragma unroll
  for (int q = 0; q < 4; ++q) {
    size_t i = base + (size_t)tid * 4 + q;
    int x = (i < (size_t)n) ? in[i] : 0;
    v[q] = acc;
    acc += x;
  }
  sh[tid] = acc;
  __syncthreads();
  for (int off = 1; off < 256; off <<= 1) {
    int y = (tid >= off) ? sh[tid - off] : 0;
    __syncthreads();
    sh[tid] += y;
    __syncthreads();
  }
  int excl = (tid == 0) ? 0 : sh[tid - 1];
  if (tid == 255) bs[blk] = sh[255];
#pragma unroll
  for (int q = 0; q < 4; ++q) {
    size_t i = base + (size_t)tid * 4 + q;
    if (i < (size_t)n) out[i] = excl + v[q];
  }
}

__global__ __launch_bounds__(1024) void kscan2b(int* __restrict__ bsA, int nbA,
                                                int* __restrict__ bsB, int nbB) {
  __shared__ int sh[1024];
  int* bs = (blockIdx.x == 0) ? bsA : bsB;
  int nb = (blockIdx.x == 0) ? nbA : nbB;
  int tid = threadIdx.x;
  sh[tid] = (tid < nb) ? bs[tid] : 0;
  __syncthreads();
  for (int off = 1; off < 1024; off <<= 1) {
    int y = (tid >= off) ? sh[tid - off] : 0;
    __syncthreads();
    sh[tid] += y;
    __syncthreads();
  }
  if (tid < nb) bs[tid] = (tid == 0) ? 0 : sh[tid - 1];
}

__global__ __launch_bounds__(256) void kscan3b(
    int* __restrict__ outA, const int* __restrict__ bsA, int nA, int totalA,
    int* __restrict__ outB, const int* __restrict__ bsB, int nB, int totalB) {
  int i = blockIdx.x * 256 + threadIdx.x;
  if (i <= nA) {
    if (i < nA) outA[i] += bsA[i >> 10];
    else outA[nA] = totalA;
  } else {
    int j = i - (nA + 1);
    if (j < nB) outB[j] += bsB[j >> 10];
    else if (j == nB) outB[nB] = totalB;
  }
}

// ---------------- combined prep: triplet scatter + edge scatter + weight pack
__global__ __launch_bounds__(256) void kprep_all(
    const int* __restrict__ tji, const int* __restrict__ toff, int* __restrict__ tcnt,
    int* __restrict__ tids, const float* __restrict__ afeat, u16* __restrict__ afeat_s,
    const int* __restrict__ edst, const int* __restrict__ noff, int* __restrict__ ncnt,
    int* __restrict__ eslot, const float* __restrict__ dir, float* __restrict__ dir_s,
    const float* __restrict__ Wt1, const float* __restrict__ Wt2,
    const float* __restrict__ Wm1, const float* __restrict__ Wm2,
    const float* __restrict__ Wu1, const float* __restrict__ Wu2,
    const float* __restrict__ Wg1, const float* __restrict__ Wg2,
    u16* __restrict__ Pt1, u16* __restrict__ Pt2,
    u16* __restrict__ Pm1, u16* __restrict__ Pm2,
    u16* __restrict__ Pu1, u16* __restrict__ Pu2,
    u16* __restrict__ Pg1, u16* __restrict__ Pg2) {
  int i = blockIdx.x * 256 + threadIdx.x;
  if (i < NT) {
    int k = tji[i];
    int slot = toff[k] + (atomicSub(&tcnt[k], 1) - 1);
    tids[slot] = i;
    const float4* src = (const float4*)(afeat + (size_t)i * 16);
    uint2* dst = (uint2*)(afeat_s + (size_t)slot * 16);
#pragma unroll
    for (int q = 0; q < 4; ++q) {
      float4 v = src[q];
      uint2 p;
      p.x = pk2(v.x, v.y);
      p.y = pk2(v.z, v.w);
      dst[q] = p;
    }
  } else if (i < NT + NE) {
    int j = i - NT;
    int k = edst[j];
    int slot = noff[k] + (atomicSub(&ncnt[k], 1) - 1);
    eslot[j] = slot;
    dir_s[(size_t)slot * 3 + 0] = dir[(size_t)j * 3 + 0];
    dir_s[(size_t)slot * 3 + 1] = dir[(size_t)j * 3 + 1];
    dir_s[(size_t)slot * 3 + 2] = dir[(size_t)j * 3 + 2];
  } else {
    int g = i - NT - NE;
    int f = g >> 6, l = g & 63;
    const float* W; u16* out; int K, N, fl;
    if (f < 20)       { W = Wt1; out = Pt1; K = 144; N = 64;  fl = f; }
    else if (f < 28)  { W = Wt2; out = Pt2; K = 64;  N = 64;  fl = f - 20; }
    else if (f < 60)  { W = Wm1; out = Pm1; K = 256; N = 64;  fl = f - 28; }
    else if (f < 76)  { W = Wm2; out = Pm2; K = 64;  N = 128; fl = f - 60; }
    else if (f < 100) { W = Wu1; out = Pu1; K = 192; N = 64;  fl = f - 76; }
    else if (f < 108) { W = Wu2; out = Pu2; K = 64;  N = 64;  fl = f - 100; }
    else if (f < 132) { W = Wg1; out = Pg1; K = 192; N = 64;  fl = f - 108; }
    else if (f < 140) { W = Wg2; out = Pg2; K = 64;  N = 64;  fl = f - 132; }
    else return;
    int nt = fl % (N / 16);
    int kt = fl / (N / 16);
    int k0 = kt * 32 + (l >> 4) * 8;
    int n = nt * 16 + (l & 15);
    u16 vals[8];
#pragma unroll
    for (int j = 0; j < 8; ++j) {
      int kk = k0 + j;
      vals[j] = (kk < K) ? f2b(W[(size_t)kk * N + n]) : (u16)0;
    }
    uint4* dst = (uint4*)(out + (size_t)fl * 512 + l * 8);
    uint4 p;
    p.x = (u32)vals[0] | ((u32)vals[1] << 16);
    p.y = (u32)vals[2] | ((u32)vals[3] << 16);
    p.z = (u32)vals[4] | ((u32)vals[5] << 16);
    p.w = (u32)vals[6] | ((u32)vals[7] << 16);
    *dst = p;
  }
}

// ---------------- Kernel T (MFMA + gload_lds staging): triplet MLP in slot order
// Regions: S[0]=erbf[kj], S[1]=erbf[ji] (gload), S[2]=afeat+pad (regular). 24KB.
__global__ __launch_bounds__(256) void ktrip_mfma(
    const int* __restrict__ tkj, const int* __restrict__ tji,
    const u16* __restrict__ erbf_bf, const u16* __restrict__ afeat_s,
    const int* __restrict__ tids,
    const u16* __restrict__ Wp1, const float* __restrict__ b1,
    const u16* __restrict__ Wp2, const float* __restrict__ b2,
    u16* __restrict__ tmsg_s) {
  __shared__ __align__(16) u16 S[3][64 * 64];
  u16* Hs = &S[0][0];   // overlay after layer 1 (S[0] dead)
  u16* OS = &S[1][0];   // out-stage [64][64] (S[1] dead after layer 1)
  const int tid = threadIdx.x;
  const int l = tid & 63;
  const int w = tid >> 6;
  const int st0 = blockIdx.x * 64;

  // gload volleys: regions 0,1, rows w*16..w*16+15 in 2 volleys of 8
  {
    int wr = w * 16;
#pragma unroll
    for (int v = 0; v < 2; ++v) {
      int br = wr + v * 8;
      int r = br + (l >> 3);
      int sch = (l & 7) ^ (r & 7);
      int t = tids[st0 + r];
      gload16(erbf_bf + (size_t)tkj[t] * 64 + sch * 8, &S[0][br * 64]);
      gload16(erbf_bf + (size_t)tji[t] * 64 + sch * 8, &S[1][br * 64]);
    }
  }
  // region 2: afeat cols 0..15, zeros 16..31 (cols 32..63 never read)
  {
    int r = tid >> 2, c = (tid & 3) * 4;
    uint2 p2 = *(const uint2*)&afeat_s[(size_t)(st0 + r) * 16 + c];
    *(uint2*)&S[2][lx<64>(r, c)] = p2;
  }
#pragma unroll
  for (int i = 0; i < 2; ++i) {
    int idx = i * 256 + tid;
    int r = idx >> 3, c = 16 + (idx & 7) * 2;
    *(u32*)&S[2][lx<64>(r, c)] = 0;
  }
  __syncthreads();

  // layer 1: K=160, ks 0..4; region = ks>>1
  f32x4 acc1[4];
  {
    float bias = b1[w * 16 + (l & 15)];
#pragma unroll
    for (int mt = 0; mt < 4; ++mt) acc1[mt] = (f32x4){bias, bias, bias, bias};
#pragma unroll
    for (int ks = 0; ks < 5; ++ks) {
      short8 bf = *(const short8*)(Wp1 + ((size_t)(ks * 4 + w) * 64 + l) * 8);
      const u16* R = &S[ks >> 1][0];
      int cc = (ks & 1) * 32 + ((l >> 4) << 3);
#pragma unroll
      for (int mt = 0; mt < 4; ++mt) {
        short8 af = *(const short8*)&R[lx<64>(mt * 16 + (l & 15), cc)];
        acc1[mt] = __builtin_amdgcn_mfma_f32_16x16x32_bf16(af, bf, acc1[mt], 0, 0, 0);
      }
    }
  }
  __syncthreads();  // all reads done before Hs overlay
#pragma unroll
  for (int mt = 0; mt < 4; ++mt)
#pragma unroll
    for (int q = 0; q < 4; ++q) {
      int r = mt * 16 + (l >> 4) * 4 + q;
      Hs[lx<64>(r, w * 16 + (l & 15))] = f2b(silu_f(acc1[mt][q]));
    }
  __syncthreads();

  f32x4 acc2[4];
  {
    float bias = b2[w * 16 + (l & 15)];
#pragma unroll
    for (int mt = 0; mt < 4; ++mt) acc2[mt] = (f32x4){bias, bias, bias, bias};
    for (int ks = 0; ks < 2; ++ks) {
      short8 bf = *(const short8*)(Wp2 + ((size_t)(ks * 4 + w) * 64 + l) * 8);
#pragma unroll
      for (int mt = 0; mt < 4; ++mt) {
        short8 af = *(const short8*)&Hs[lx<64>(mt * 16 + (l & 15), ks * 32 + ((l >> 4) << 3))];
        acc2[mt] = __builtin_amdgcn_mfma_f32_16x16x32_bf16(af, bf, acc2[mt], 0, 0, 0);
      }
    }
  }
  __syncthreads();  // before OS overlay (S[1] dead)
#pragma unroll
  for (int mt = 0; mt < 4; ++mt)
#pragma unroll
    for (int q = 0; q < 4; ++q) {
      int r = mt * 16 + (l >> 4) * 4 + q;
      OS[lx<64>(r, w * 16 + (l & 15))] = f2b(acc2[mt][q]);
    }
  __syncthreads();
  for (int i = 0; i < 2; ++i) {
    int idx = i * 256 + tid;
    int r = idx >> 3, c0 = (idx & 7) << 3;
    uint4 val = *(const uint4*)&OS[lx<64>(r, c0)];
    *(uint4*)(tmsg_s + (size_t)(st0 + r) * 64 + c0) = val;
  }
}

// ---------------- Kernel M (MFMA + gload_lds staging): natural edge order -> msg_s[eslot]
// Regions: S[0]=s[src], S[1]=s[dst], S[2]=erbf (gload), S[3]=aagg (register sum). 32KB.
__global__ __launch_bounds__(256) void kmsg_mfma(
    const int* __restrict__ eidx, const u16* __restrict__ s_bf,
    const u16* __restrict__ erbf_bf,
    const int* __restrict__ toff, const u16* __restrict__ tmsg_s,
    const int* __restrict__ eslot,
    const u16* __restrict__ Wp1, const float* __restrict__ b1,
    const u16* __restrict__ Wp2, const float* __restrict__ b2,
    u16* __restrict__ msg_s) {
  __shared__ __align__(16) u16 S[4][64 * 64];
  u16* Hs = &S[0][0];   // overlay after layer 1
  u16* OS = &S[1][0];   // out-stage [64][128] over S[1]+S[2]
  const int tid = threadIdx.x;
  const int l = tid & 63;
  const int w = tid >> 6;
  const int e0 = blockIdx.x * 64;

  // gload volleys: regions 0,1,2
  {
    int wr = w * 16;
#pragma unroll
    for (int v = 0; v < 2; ++v) {
      int br = wr + v * 8;
      int r = br + (l >> 3);
      int sch = (l & 7) ^ (r & 7);
      gload16(s_bf + (size_t)eidx[e0 + r] * 64 + sch * 8, &S[0][br * 64]);
      gload16(s_bf + (size_t)eidx[NE + e0 + r] * 64 + sch * 8, &S[1][br * 64]);
      gload16(erbf_bf + (size_t)(e0 + r) * 64 + sch * 8, &S[2][br * 64]);
    }
  }
  // region 3: aagg contiguous CSR sum (512 tasks)
#pragma unroll
  for (int it = 0; it < 2; ++it) {
    int idx = it * 256 + tid;
    int r = idx >> 3, ch = idx & 7;
    int e = e0 + r;
    int r0 = toff[e], r1 = toff[e + 1];
    float a[8];
#pragma unroll
    for (int j = 0; j < 8; ++j) a[j] = 0.f;
    for (int ri = r0; ri < r1; ++ri) {
      uint4 pk = *(const uint4*)&tmsg_s[(size_t)ri * 64 + ch * 8];
      a[0] += b2f((u16)(pk.x & 0xffff)); a[1] += b2f((u16)(pk.x >> 16));
      a[2] += b2f((u16)(pk.y & 0xffff)); a[3] += b2f((u16)(pk.y >> 16));
      a[4] += b2f((u16)(pk.z & 0xffff)); a[5] += b2f((u16)(pk.z >> 16));
      a[6] += b2f((u16)(pk.w & 0xffff)); a[7] += b2f((u16)(pk.w >> 16));
    }
    uint4 p;
    p.x = pk2(a[0], a[1]);
    p.y = pk2(a[2], a[3]);
    p.z = pk2(a[4], a[5]);
    p.w = pk2(a[6], a[7]);
    *(uint4*)&S[3][lx<64>(r, ch * 8)] = p;
  }
  __syncthreads();

  // layer 1: K=256, ks 0..7; region = ks>>1
  f32x4 acc1[4];
  {
    float bias = b1[w * 16 + (l & 15)];
#pragma unroll
    for (int mt = 0; mt < 4; ++mt) acc1[mt] = (f32x4){bias, bias, bias, bias};
#pragma unroll
    for (int ks = 0; ks < 8; ++ks) {
      short8 bf = *(const short8*)(Wp1 + ((size_t)(ks * 4 + w) * 64 + l) * 8);
      const u16* R = &S[ks >> 1][0];
      int cc = (ks & 1) * 32 + ((l >> 4) << 3);
#pragma unroll
      for (int mt = 0; mt < 4; ++mt) {
        short8 af = *(const short8*)&R[lx<64>(mt * 16 + (l & 15), cc)];
        acc1[mt] = __builtin_amdgcn_mfma_f32_16x16x32_bf16(af, bf, acc1[mt], 0, 0, 0);
      }
    }
  }
  __syncthreads();  // all reads done before Hs overlay
#pragma unroll
  for (int mt = 0; mt < 4; ++mt)
#pragma unroll
    for (int q = 0; q < 4; ++q) {
      int r = mt * 16 + (l >> 4) * 4 + q;
      Hs[lx<64>(r, w * 16 + (l & 15))] = f2b(silu_f(acc1[mt][q]));
    }
  __syncthreads();

  f32x4 acc2[2][4];
#pragma unroll
  for (int pp = 0; pp < 2; ++pp) {
    int nt = w * 2 + pp;
    float bias = b2[nt * 16 + (l & 15)];
#pragma unroll
    for (int mt = 0; mt < 4; ++mt) acc2[pp][mt] = (f32x4){bias, bias, bias, bias};
    for (int ks = 0; ks < 2; ++ks) {
      short8 bf = *(const short8*)(Wp2 + ((size_t)(ks * 8 + nt) * 64 + l) * 8);
#pragma unroll
      for (int mt = 0; mt < 4; ++mt) {
        short8 af = *(const short8*)&Hs[lx<64>(mt * 16 + (l & 15), ks * 32 + ((l >> 4) << 3))];
        acc2[pp][mt] = __builtin_amdgcn_mfma_f32_16x16x32_bf16(af, bf, acc2[pp][mt], 0, 0, 0);
      }
    }
  }
  __syncthreads();  // before OS overlay (S[1],S[2] dead)
#pragma unroll
  for (int pp = 0; pp < 2; ++pp)
#pragma unroll
    for (int mt = 0; mt < 4; ++mt)
#pragma unroll
      for (int q = 0; q < 4; ++q) {
        int r = mt * 16 + (l >> 4) * 4 + q;
        OS[lx<128>(r, (w * 2 + pp) * 16 + (l & 15))] = f2b(acc2[pp][mt][q]);
      }
  __syncthreads();
  for (int i = 0; i < 4; ++i) {
    int idx = i * 256 + tid;
    int r = idx >> 4, c0 = (idx & 15) << 3;
    int slot = eslot[e0 + r];
    uint4 val = *(const uint4*)&OS[lx<128>(r, c0)];
    *(uint4*)(msg_s + (size_t)slot * 128 + c0) = val;
  }
}

// ---------------- Kernel A (proven): streaming CSR reduction, 4 rows/iter, uint4 loads
__global__ __launch_bounds__(256) void kagg(
    const int* __restrict__ noff, const u16* __restrict__ msg_s,
    const float* __restrict__ dir_s,
    u16* __restrict__ aggs_bf, float* __restrict__ aggv) {
  const int lane = threadIdx.x & 63;
  const int wv = threadIdx.x >> 6;
  const int n = blockIdx.x * 4 + wv;
  if (n >= NN) return;
  const int r0 = noff[n], r1 = noff[n + 1];
  const int lrow = lane >> 4, lcol = lane & 15;
  const bool is_ms = (lcol < 8);

  float a[8];
  float v0[8], v1[8], v2[8];
#pragma unroll
  for (int j = 0; j < 8; ++j) { a[j] = 0.f; v0[j] = 0.f; v1[j] = 0.f; v2[j] = 0.f; }

  for (int r4 = r0; r4 < r1; r4 += 4) {
    int r = r4 + lrow;
    if (r < r1) {
      uint4 pk = *(const uint4*)&msg_s[(size_t)r * 128 + lcol * 8];
      float x[8];
      x[0] = b2f((u16)(pk.x & 0xffff)); x[1] = b2f((u16)(pk.x >> 16));
      x[2] = b2f((u16)(pk.y & 0xffff)); x[3] = b2f((u16)(pk.y >> 16));
      x[4] = b2f((u16)(pk.z & 0xffff)); x[5] = b2f((u16)(pk.z >> 16));
      x[6] = b2f((u16)(pk.w & 0xffff)); x[7] = b2f((u16)(pk.w >> 16));
      if (is_ms) {
#pragma unroll
        for (int j = 0; j < 8; ++j) a[j] += x[j];
      } else {
        float dx = dir_s[(size_t)r * 3 + 0];
        float dy = dir_s[(size_t)r * 3 + 1];
        float dz = dir_s[(size_t)r * 3 + 2];
#pragma unroll
        for (int j = 0; j < 8; ++j) {
          v0[j] += x[j] * dx; v1[j] += x[j] * dy; v2[j] += x[j] * dz;
        }
      }
    }
  }
#pragma unroll
  for (int j = 0; j < 8; ++j) {
    a[j] += __shfl_xor(a[j], 16);  a[j] += __shfl_xor(a[j], 32);
    v0[j] += __shfl_xor(v0[j], 16); v0[j] += __shfl_xor(v0[j], 32);
    v1[j] += __shfl_xor(v1[j], 16); v1[j] += __shfl_xor(v1[j], 32);
    v2[j] += __shfl_xor(v2[j], 16); v2[j] += __shfl_xor(v2[j], 32);
  }
  if (lrow == 0) {
    if (is_ms) {
      uint4 p;
      p.x = pk2(a[0], a[1]);
      p.y = pk2(a[2], a[3]);
      p.z = pk2(a[4], a[5]);
      p.w = pk2(a[6], a[7]);
      *(uint4*)&aggs_bf[(size_t)n * 64 + lcol * 8] = p;
    } else {
      int c0 = (lcol - 8) * 8;
      float* av = aggv + (size_t)n * 192 + (size_t)c0 * 3;
      float4 o0 = {v0[0], v1[0], v2[0], v0[1]};
      float4 o1 = {v1[1], v2[1], v0[2], v1[2]};
      float4 o2 = {v2[2], v0[3], v1[3], v2[3]};
      float4 o3 = {v0[4], v1[4], v2[4], v0[5]};
      float4 o4 = {v1[5], v2[5], v0[6], v1[6]};
      float4 o5 = {v2[6], v0[7], v1[7], v2[7]};
      float4* av4 = (float4*)av;
      av4[0] = o0; av4[1] = o1; av4[2] = o2; av4[3] = o3; av4[4] = o4; av4[5] = o5;
    }
  }
}

// ---------------- Kernel N (MFMA, proven)
__global__ __launch_bounds__(256) void knode_mfma(
    const u16* __restrict__ s_bf, const float* __restrict__ v,
    const u16* __restrict__ aggs_bf, const float* __restrict__ aggv,
    const u16* __restrict__ WpU1, const float* __restrict__ bU1,
    const u16* __restrict__ WpU2, const float* __restrict__ bU2,
    const u16* __restrict__ WpG1, const float* __restrict__ bG1,
    const u16* __restrict__ WpG2, const float* __restrict__ bG2,
    const float* __restrict__ lng, const float* __restrict__ lnb,
    float* __restrict__ outs, float* __restrict__ outv) {
  __shared__ __align__(16) char smem[64 * 192 * 2 + 2 * 64 * 64 * 2];  // 40KB
  u16* Xs = (u16*)smem;
  u16* Hu = (u16*)(smem + 64 * 192 * 2);
  u16* Hg = Hu + 64 * 64;
  float* Fs = (float*)smem;

  const int tid = threadIdx.x;
  const int l = tid & 63;
  const int w = tid >> 6;
  const int n0 = blockIdx.x * 64;

  for (int i = 0; i < 2; ++i) {
    int idx = i * 256 + tid;
    int r = idx >> 3, c0 = (idx & 7) << 3;
    int nr = n0 + r; if (nr >= NN) nr = NN - 1;
    uint4 a = *(const uint4*)&s_bf[(size_t)nr * 64 + c0];
    *(uint4*)&Xs[lx<192>(r, c0)] = a;
    uint4 b = *(const uint4*)&aggs_bf[(size_t)nr * 64 + c0];
    *(uint4*)&Xs[lx<192>(r, 64 + c0)] = b;
  }
  for (int it = 0; it < 16; ++it) {
    int idx = it * 256 + tid;
    int r = idx >> 6, c = idx & 63;
    int nr = n0 + r; if (nr >= NN) nr = NN - 1;
    const float* vp = v + (size_t)nr * 192 + c * 3;
    float x = vp[0], y = vp[1], z = vp[2];
    Xs[lx<192>(r, 128 + c)] = f2b(sqrtf(x * x + y * y + z * z));
  }
  __syncthreads();

  f32x4 au[4], ag[4];
  {
    float biu = bU1[w * 16 + (l & 15)], big = bG1[w * 16 + (l & 15)];
#pragma unroll
    for (int mt = 0; mt < 4; ++mt) {
      au[mt] = (f32x4){biu, biu, biu, biu};
      ag[mt] = (f32x4){big, big, big, big};
    }
    for (int ks = 0; ks < 6; ++ks) {
      short8 bu = *(const short8*)(WpU1 + ((size_t)(ks * 4 + w) * 64 + l) * 8);
      short8 bg = *(const short8*)(WpG1 + ((size_t)(ks * 4 + w) * 64 + l) * 8);
#pragma unroll
      for (int mt = 0; mt < 4; ++mt) {
        short8 af = *(const short8*)&Xs[lx<192>(mt * 16 + (l & 15), ks * 32 + ((l >> 4) << 3))];
        au[mt] = __builtin_amdgcn_mfma_f32_16x16x32_bf16(af, bu, au[mt], 0, 0, 0);
        ag[mt] = __builtin_amdgcn_mfma_f32_16x16x32_bf16(af, bg, ag[mt], 0, 0, 0);
      }
    }
  }
#pragma unroll
  for (int mt = 0; mt < 4; ++mt)
#pragma unroll
    for (int q = 0; q < 4; ++q) {
      int r = mt * 16 + (l >> 4) * 4 + q;
      Hu[lx<64>(r, w * 16 + (l & 15))] = f2b(silu_f(au[mt][q]));
      Hg[lx<64>(r, w * 16 + (l & 15))] = f2b(silu_f(ag[mt][q]));
    }
  __syncthreads();

  f32x4 ou[4], og[4];
  {
    float biu = bU2[w * 16 + (l & 15)], big = bG2[w * 16 + (l & 15)];
#pragma unroll
    for (int mt = 0; mt < 4; ++mt) {
      ou[mt] = (f32x4){biu, biu, biu, biu};
      og[mt] = (f32x4){big, big, big, big};
    }
    for (int ks = 0; ks < 2; ++ks) {
      short8 bu = *(const short8*)(WpU2 + ((size_t)(ks * 4 + w) * 64 + l) * 8);
      short8 bg = *(const short8*)(WpG2 + ((size_t)(ks * 4 + w) * 64 + l) * 8);
#pragma unroll
      for (int mt = 0; mt < 4; ++mt) {
        short8 afu = *(const short8*)&Hu[lx<64>(mt * 16 + (l & 15), ks * 32 + ((l >> 4) << 3))];
        ou[mt] = __builtin_amdgcn_mfma_f32_16x16x32_bf16(afu, bu, ou[mt], 0, 0, 0);
        short8 afg = *(const short8*)&Hg[lx<64>(mt * 16 + (l & 15), ks * 32 + ((l >> 4) << 3))];
        og[mt] = __builtin_amdgcn_mfma_f32_16x16x32_bf16(afg, bg, og[mt], 0, 0, 0);
      }
    }
  }
#pragma unroll
  for (int mt = 0; mt < 4; ++mt)
#pragma unroll
    for (int q = 0; q < 4; ++q) {
      int r = mt * 16 + (l >> 4) * 4 + q;
      ou[mt][q] += b2f(Xs[lx<192>(r, w * 16 + (l & 15))]);
    }
  __syncthreads();

#pragma unroll
  for (int mt = 0; mt < 4; ++mt)
#pragma unroll
    for (int q = 0; q < 4; ++q) {
      int r = mt * 16 + (l >> 4) * 4 + q;
      Fs[r * 68 + w * 16 + (l & 15)] = ou[mt][q];
    }
  __syncthreads();
  {
    int r = tid >> 2, c0 = (tid & 3) * 16;
    float xv[16];
#pragma unroll
    for (int j4 = 0; j4 < 4; ++j4) {
      float4 t = *(const float4*)&Fs[r * 68 + c0 + j4 * 4];
      xv[j4 * 4 + 0] = t.x; xv[j4 * 4 + 1] = t.y;
      xv[j4 * 4 + 2] = t.z; xv[j4 * 4 + 3] = t.w;
    }
    float sm = 0.f, sq = 0.f;
#pragma unroll
    for (int j = 0; j < 16; ++j) { sm += xv[j]; sq += xv[j] * xv[j]; }
    sm += __shfl_xor(sm, 1); sq += __shfl_xor(sq, 1);
    sm += __shfl_xor(sm, 2); sq += __shfl_xor(sq, 2);
    float mu = sm * (1.f / 64.f);
    float var = sq * (1.f / 64.f) - mu * mu;
    float rstd = rsqrtf(var + 1e-5f);
    if (n0 + r < NN) {
      float* op = outs + (size_t)(n0 + r) * 64 + c0;
#pragma unroll
      for (int j4 = 0; j4 < 4; ++j4) {
        float4 o;
        float y0 = (xv[j4 * 4 + 0] - mu) * rstd * lng[c0 + j4 * 4 + 0] + lnb[c0 + j4 * 4 + 0];
        float y1 = (xv[j4 * 4 + 1] - mu) * rstd * lng[c0 + j4 * 4 + 1] + lnb[c0 + j4 * 4 + 1];
        float y2 = (xv[j4 * 4 + 2] - mu) * rstd * lng[c0 + j4 * 4 + 2] + lnb[c0 + j4 * 4 + 2];
        float y3 = (xv[j4 * 4 + 3] - mu) * rstd * lng[c0 + j4 * 4 + 3] + lnb[c0 + j4 * 4 + 3];
        o.x = silu_f(y0); o.y = silu_f(y1); o.z = silu_f(y2); o.w = silu_f(y3);
        *(float4*)(op + j4 * 4) = o;
      }
    }
  }
  __syncthreads();

#pragma unroll
  for (int mt = 0; mt < 4; ++mt)
#pragma unroll
    for (int q = 0; q < 4; ++q) {
      int r = mt * 16 + (l >> 4) * 4 + q;
      Fs[r * 68 + w * 16 + (l & 15)] = og[mt][q];
    }
  __syncthreads();
  {
    int r = tid >> 2, c0 = (tid & 3) * 16;
    int nr = n0 + r;
    if (nr < NN) {
      float gate[16];
#pragma unroll
      for (int j = 0; j < 16; ++j) gate[j] = sigm_f(Fs[r * 68 + c0 + j]);
      const float4* vp = (const float4*)(v + (size_t)nr * 192 + c0 * 3);
      const float4* ap = (const float4*)(aggv + (size_t)nr * 192 + c0 * 3);
      float4* op = (float4*)(outv + (size_t)nr * 192 + c0 * 3);
#pragma unroll
      for (int j4 = 0; j4 < 12; ++j4) {
        float4 vv = vp[j4], av = ap[j4], o;
        o.x = vv.x + gate[(j4 * 4 + 0) / 3] * av.x;
        o.y = vv.y + gate[(j4 * 4 + 1) / 3] * av.y;
        o.z = vv.z + gate[(j4 * 4 + 2) / 3] * av.z;
        o.w = vv.w + gate[(j4 * 4 + 3) / 3] * av.w;
        op[j4] = o;
      }
    }
  }
}

extern "C" void kernel_launch(void* const* d_in, const int* in_sizes, int n_in,
                              void* d_out, int out_size, void* d_ws, size_t ws_size,
                              hipStream_t stream) {
  const float* s     = (const float*)d_in[0];
  const float* v     = (const float*)d_in[1];
  const int*   eidx  = (const int*)d_in[2];
  const float* erbf  = (const float*)d_in[3];
  const float* edir  = (const float*)d_in[4];
  const int*   tkj   = (const int*)d_in[5];
  const int*   tji   = (const int*)d_in[6];
  const float* afeat = (const float*)d_in[7];
  const float* W_t1  = (const float*)d_in[8];
  const float* b_t1  = (const float*)d_in[9];
  const float* W_t2  = (const float*)d_in[10];
  const float* b_t2  = (const float*)d_in[11];
  const float* W_m1  = (const float*)d_in[12];
  const float* b_m1  = (const float*)d_in[13];
  const float* W_m2  = (const float*)d_in[14];
  const float* b_m2  = (const float*)d_in[15];
  const float* W_u1  = (const float*)d_in[16];
  const float* b_u1  = (const float*)d_in[17];
  const float* W_u2  = (const float*)d_in[18];
  const float* b_u2  = (const float*)d_in[19];
  const float* W_g1  = (const float*)d_in[20];
  const float* b_g1  = (const float*)d_in[21];
  const float* W_g2  = (const float*)d_in[22];
  const float* b_g2  = (const float*)d_in[23];
  const float* ln_g  = (const float*)d_in[24];
  const float* ln_b  = (const float*)d_in[25];

  char* w = (char*)d_ws;
  auto alloc = [&](size_t bytes) -> char* {
    char* p = w;
    w += (bytes + 255) & ~(size_t)255;
    return p;
  };
  int* tcnt  = (int*)alloc((size_t)NE * 4);
  int* ncnt  = (int*)alloc((size_t)NN * 4);
  size_t zspan = (size_t)((char*)(ncnt + NN) - (char*)tcnt);
  int* toff  = (int*)alloc((size_t)(NE + 1) * 4);
  int* noff  = (int*)alloc((size_t)(NN + 1) * 4);
  int* tids  = (int*)alloc((size_t)NT * 4);
  int* eslot = (int*)alloc((size_t)NE * 4);
  int* bsum  = (int*)alloc(2048 * 4);
  float* dir_s = (float*)alloc((size_t)NE * 3 * 4);
  u16* msg_s  = (u16*)alloc((size_t)NE * 128 * 2);       // 204.8 MB
  u16* tmsg_s = (u16*)alloc((size_t)NT * 64 * 2);        // 102.4 MB
  u16* erbf_bf = (u16*)alloc((size_t)NE * 64 * 2);       // 102.4 MB
  u16* s_bf    = (u16*)alloc((size_t)NN * 64 * 2);       // 6.4 MB
  u16* Wp_t1 = (u16*)alloc((size_t)5 * 4 * 512 * 2);
  u16* Wp_t2 = (u16*)alloc((size_t)2 * 4 * 512 * 2);
  u16* Wp_m1 = (u16*)alloc((size_t)8 * 4 * 512 * 2);
  u16* Wp_m2 = (u16*)alloc((size_t)2 * 8 * 512 * 2);
  u16* Wp_u1 = (u16*)alloc((size_t)6 * 4 * 512 * 2);
  u16* Wp_u2 = (u16*)alloc((size_t)2 * 4 * 512 * 2);
  u16* Wp_g1 = (u16*)alloc((size_t)6 * 4 * 512 * 2);
  u16* Wp_g2 = (u16*)alloc((size_t)2 * 4 * 512 * 2);
  u16* afeat_s = msg_s;            // alias: read only by ktrip; msg_s written later by kmsg
  float* aggv = (float*)tmsg_s;    // alias: tmsg_s dead after kmsg
  u16* aggs_bf = tmsg_s + (size_t)NN * 384;

  hipMemsetAsync(tcnt, 0, zspan, stream);

  kcvt_hist<<<((NE + NN) * 16 + NT + NE + 255) / 256, 256, 0, stream>>>(
      erbf, erbf_bf, s, s_bf, tji, eidx + NE, tcnt, ncnt);

  const int Bt = (NE + 1023) / 1024, Bn = (NN + 1023) / 1024;
  kscan1b<<<Bt + Bn, 256, 0, stream>>>(tcnt, NE, toff, bsum, Bt, ncnt, NN, noff, bsum + 1024);
  kscan2b<<<2, 1024, 0, stream>>>(bsum, Bt, bsum + 1024, Bn);
  kscan3b<<<(NE + 1 + NN + 1 + 255) / 256, 256, 0, stream>>>(toff, bsum, NE, NT,
                                                             noff, bsum + 1024, NN, NE);

  kprep_all<<<(NT + NE + 140 * 64 + 255) / 256, 256, 0, stream>>>(
      tji, toff, tcnt, tids, afeat, afeat_s,
      eidx + NE, noff, ncnt, eslot, edir, dir_s,
      W_t1, W_t2, W_m1, W_m2, W_u1, W_u2, W_g1, W_g2,
      Wp_t1, Wp_t2, Wp_m1, Wp_m2, Wp_u1, Wp_u2, Wp_g1, Wp_g2);

  ktrip_mfma<<<NT / 64, 256, 0, stream>>>(tkj, tji, erbf_bf, afeat_s, tids,
                                          Wp_t1, b_t1, Wp_t2, b_t2, tmsg_s);
  kmsg_mfma<<<NE / 64, 256, 0, stream>>>(eidx, s_bf, erbf_bf, toff, tmsg_s, eslot,
                                         Wp_m1, b_m1, Wp_m2, b_m2, msg_s);
  kagg<<<(NN + 3) / 4, 256, 0, stream>>>(noff, msg_s, dir_s, aggs_bf, aggv);

  float* out_s = (float*)d_out;
  float* out_v = out_s + (size_t)NN * 64;
  knode_mfma<<<(NN + 63) / 64, 256, 0, stream>>>(s_bf, v, aggs_bf, aggv,
                                                 Wp_u1, b_u1, Wp_u2, b_u2,
                                                 Wp_g1, b_g1, Wp_g2, b_g2,
                                                 ln_g, ln_b, out_s, out_v);
}

// Round 15
// 597.307 us; speedup vs baseline: 1.0380x; 1.0189x over previous
//
#include <hip/hip_runtime.h>
#include <cstdint>
#include <cstddef>

#define NN 50000
#define NE 800000
#define NT 800000

typedef unsigned short u16;
typedef unsigned int u32;
typedef __attribute__((ext_vector_type(8))) short short8;
typedef __attribute__((ext_vector_type(4))) float f32x4;

__device__ __forceinline__ float silu_f(float x) { return x / (1.f + __expf(-x)); }
__device__ __forceinline__ float sigm_f(float x) { return 1.f / (1.f + __expf(-x)); }
__device__ __forceinline__ u16 f2b(float x) {
  u32 u = __float_as_uint(x);
  u32 r = u + 0x7fffu + ((u >> 16) & 1u);
  return (u16)(r >> 16);
}
__device__ __forceinline__ float b2f(u16 h) { return __uint_as_float(((u32)h) << 16); }
__device__ __forceinline__ u32 pk2(float a, float b) {
  return (u32)f2b(a) | ((u32)f2b(b) << 16);
}

// XOR-swizzled LDS elem offset for row-major [*][RW] u16 tiles (16B-chunk ^ (r&7)).
template <int RW>
__device__ __forceinline__ int lx(int r, int c) {
  return r * RW + ((((c >> 3) ^ (r & 7)) << 3) | (c & 7));
}

// async HBM -> LDS, 16B per lane, dest = lds + lane*16 (wave-uniform base)
__device__ __forceinline__ void gload16(const void* g, void* l) {
  __builtin_amdgcn_global_load_lds((const __attribute__((address_space(1))) void*)g,
                                   (__attribute__((address_space(3))) void*)l, 16, 0, 0);
}

// ---------------- merged bf16 conversion + histograms (1 launch)
__global__ __launch_bounds__(256) void kcvt_hist(
    const float* __restrict__ erbf, u16* __restrict__ erbf_bf,
    const float* __restrict__ s, u16* __restrict__ s_bf,
    const int* __restrict__ tji, const int* __restrict__ edst,
    int* __restrict__ tcnt, int* __restrict__ ncnt) {
  int i = blockIdx.x * 256 + threadIdx.x;
  const int NCVT = (NE + NN) * 16;
  if (i < NCVT) {
    const float* in; u16* out; int j;
    if (i < NE * 16) { in = erbf; out = erbf_bf; j = i; }
    else { in = s; out = s_bf; j = i - NE * 16; }
    float4 v = ((const float4*)in)[j];
    uint2 p;
    p.x = pk2(v.x, v.y);
    p.y = pk2(v.z, v.w);
    ((uint2*)out)[j] = p;
  } else {
    int j = i - NCVT;
    if (j < NT) atomicAdd(&tcnt[tji[j]], 1);
    else {
      j -= NT;
      if (j < NE) atomicAdd(&ncnt[edst[j]], 1);
    }
  }
}

// ---------------- combined 2-range scans (proven)
__global__ __launch_bounds__(256) void kscan1b(
    const int* __restrict__ inA, int nA, int* __restrict__ outA, int* __restrict__ bsA, int BA,
    const int* __restrict__ inB, int nB, int* __restrict__ outB, int* __restrict__ bsB) {
  __shared__ int sh[256];
  const int* in; int n; int* out; int* bs; int blk;
  if ((int)blockIdx.x < BA) { in = inA; n = nA; out = outA; bs = bsA; blk = blockIdx.x; }
  else { in = inB; n = nB; out = outB; bs = bsB; blk = blockIdx.x - BA; }
  int tid = threadIdx.x;
  size_t base = (size_t)blk * 1024;
  int v[4];
  int acc = 0;
#pragma unroll
  for (int q = 0; q < 4; ++q) {
    size_t i = base + (size_t)tid * 4 + q;
    int x = (i < (size_t)n) ? in[i] : 0;
    v[q] = acc;
    acc += x;
  }
  sh[tid] = acc;
  __syncthreads();
  for (int off = 1; off < 256; off <<= 1) {
    int y = (tid >= off) ? sh[tid - off] : 0;
    __syncthreads();
    sh[tid] += y;
    __syncthreads();
  }
  int excl = (tid == 0) ? 0 : sh[tid - 1];
  if (tid == 255) bs[blk] = sh[255];
#pragma unroll
  for (int q = 0; q < 4; ++q) {
    size_t i = base + (size_t)tid * 4 + q;
    if (i < (size_t)n) out[i] = excl + v[q];
  }
}

__global__ __launch_bounds__(1024) void kscan2b(int* __restrict__ bsA, int nbA,
                                                int* __restrict__ bsB, int nbB) {
  __shared__ int sh[1024];
  int* bs = (blockIdx.x == 0) ? bsA : bsB;
  int nb = (blockIdx.x == 0) ? nbA : nbB;
  int tid = threadIdx.x;
  sh[tid] = (tid < nb) ? bs[tid] : 0;
  __syncthreads();
  for (int off = 1; off < 1024; off <<= 1) {
    int y = (tid >= off) ? sh[tid - off] : 0;
    __syncthreads();
    sh[tid] += y;
    __syncthreads();
  }
  if (tid < nb) bs[tid] = (tid == 0) ? 0 : sh[tid - 1];
}

__global__ __launch_bounds__(256) void kscan3b(
    int* __restrict__ outA, const int* __restrict__ bsA, int nA, int totalA,
    int* __restrict__ outB, const int* __restrict__ bsB, int nB, int totalB) {
  int i = blockIdx.x * 256 + threadIdx.x;
  if (i <= nA) {
    if (i < nA) outA[i] += bsA[i >> 10];
    else outA[nA] = totalA;
  } else {
    int j = i - (nA + 1);
    if (j < nB) outB[j] += bsB[j >> 10];
    else if (j == nB) outB[nB] = totalB;
  }
}

// ---------------- combined prep: triplet scatter + edge scatter + weight pack
__global__ __launch_bounds__(256) void kprep_all(
    const int* __restrict__ tji, const int* __restrict__ toff, int* __restrict__ tcnt,
    int* __restrict__ tids,
    const int* __restrict__ edst, const int* __restrict__ noff, int* __restrict__ ncnt,
    int* __restrict__ eslot, const float* __restrict__ dir, float* __restrict__ dir_s,
    const float* __restrict__ Wt1, const float* __restrict__ Wt2,
    const float* __restrict__ Wm1, const float* __restrict__ Wm2,
    const float* __restrict__ Wu1, const float* __restrict__ Wu2,
    const float* __restrict__ Wg1, const float* __restrict__ Wg2,
    u16* __restrict__ Pt1, u16* __restrict__ Pt2,
    u16* __restrict__ Pm1, u16* __restrict__ Pm2,
    u16* __restrict__ Pu1, u16* __restrict__ Pu2,
    u16* __restrict__ Pg1, u16* __restrict__ Pg2) {
  int i = blockIdx.x * 256 + threadIdx.x;
  if (i < NT) {
    int k = tji[i];
    int slot = toff[k] + (atomicSub(&tcnt[k], 1) - 1);
    tids[slot] = i;
  } else if (i < NT + NE) {
    int j = i - NT;
    int k = edst[j];
    int slot = noff[k] + (atomicSub(&ncnt[k], 1) - 1);
    eslot[j] = slot;
    dir_s[(size_t)slot * 3 + 0] = dir[(size_t)j * 3 + 0];
    dir_s[(size_t)slot * 3 + 1] = dir[(size_t)j * 3 + 1];
    dir_s[(size_t)slot * 3 + 2] = dir[(size_t)j * 3 + 2];
  } else {
    int g = i - NT - NE;
    int f = g >> 6, l = g & 63;
    const float* W; u16* out; int K, N, fl;
    if (f < 20)       { W = Wt1; out = Pt1; K = 144; N = 64;  fl = f; }
    else if (f < 28)  { W = Wt2; out = Pt2; K = 64;  N = 64;  fl = f - 20; }
    else if (f < 60)  { W = Wm1; out = Pm1; K = 256; N = 64;  fl = f - 28; }
    else if (f < 76)  { W = Wm2; out = Pm2; K = 64;  N = 128; fl = f - 60; }
    else if (f < 100) { W = Wu1; out = Pu1; K = 192; N = 64;  fl = f - 76; }
    else if (f < 108) { W = Wu2; out = Pu2; K = 64;  N = 64;  fl = f - 100; }
    else if (f < 132) { W = Wg1; out = Pg1; K = 192; N = 64;  fl = f - 108; }
    else if (f < 140) { W = Wg2; out = Pg2; K = 64;  N = 64;  fl = f - 132; }
    else return;
    int nt = fl % (N / 16);
    int kt = fl / (N / 16);
    int k0 = kt * 32 + (l >> 4) * 8;
    int n = nt * 16 + (l & 15);
    u16 vals[8];
#pragma unroll
    for (int j = 0; j < 8; ++j) {
      int kk = k0 + j;
      vals[j] = (kk < K) ? f2b(W[(size_t)kk * N + n]) : (u16)0;
    }
    uint4* dst = (uint4*)(out + (size_t)fl * 512 + l * 8);
    uint4 p;
    p.x = (u32)vals[0] | ((u32)vals[1] << 16);
    p.y = (u32)vals[2] | ((u32)vals[3] << 16);
    p.z = (u32)vals[4] | ((u32)vals[5] << 16);
    p.w = (u32)vals[6] | ((u32)vals[7] << 16);
    *dst = p;
  }
}

// ---------------- Kernel T (MFMA + gload_lds staging): triplet MLP in slot order
// Regions: S[0]=erbf[kj], S[1]=erbf[ji] (gload), S[2]=afeat f32 direct gather + pad. 24KB.
__global__ __launch_bounds__(256) void ktrip_mfma(
    const int* __restrict__ tkj, const int* __restrict__ tji,
    const u16* __restrict__ erbf_bf, const float* __restrict__ afeat,
    const int* __restrict__ tids,
    const u16* __restrict__ Wp1, const float* __restrict__ b1,
    const u16* __restrict__ Wp2, const float* __restrict__ b2,
    u16* __restrict__ tmsg_s) {
  __shared__ __align__(16) u16 S[3][64 * 64];
  u16* Hs = &S[0][0];   // overlay after layer 1 (S[0] dead)
  u16* OS = &S[1][0];   // out-stage [64][64] (S[1] dead after layer 1)
  const int tid = threadIdx.x;
  const int l = tid & 63;
  const int w = tid >> 6;
  const int st0 = blockIdx.x * 64;

  // gload volleys: regions 0,1, rows w*16..w*16+15 in 2 volleys of 8
  {
    int wr = w * 16;
#pragma unroll
    for (int v = 0; v < 2; ++v) {
      int br = wr + v * 8;
      int r = br + (l >> 3);
      int sch = (l & 7) ^ (r & 7);
      int t = tids[st0 + r];
      gload16(erbf_bf + (size_t)tkj[t] * 64 + sch * 8, &S[0][br * 64]);
      gload16(erbf_bf + (size_t)tji[t] * 64 + sch * 8, &S[1][br * 64]);
    }
  }
  // region 2: afeat f32 direct gather cols 0..15, zeros 16..31 (cols 32..63 never read)
  {
    int r = tid >> 2, c = (tid & 3) * 4;
    int t = tids[st0 + r];
    float4 v = *(const float4*)&afeat[(size_t)t * 16 + c];
    u32* q = (u32*)&S[2][lx<64>(r, c)];
    q[0] = pk2(v.x, v.y);
    q[1] = pk2(v.z, v.w);
  }
#pragma unroll
  for (int i = 0; i < 2; ++i) {
    int idx = i * 256 + tid;
    int r = idx >> 3, c = 16 + (idx & 7) * 2;
    *(u32*)&S[2][lx<64>(r, c)] = 0;
  }
  __syncthreads();

  // layer 1: K=160, ks 0..4; region = ks>>1
  f32x4 acc1[4];
  {
    float bias = b1[w * 16 + (l & 15)];
#pragma unroll
    for (int mt = 0; mt < 4; ++mt) acc1[mt] = (f32x4){bias, bias, bias, bias};
#pragma unroll
    for (int ks = 0; ks < 5; ++ks) {
      short8 bf = *(const short8*)(Wp1 + ((size_t)(ks * 4 + w) * 64 + l) * 8);
      const u16* R = &S[ks >> 1][0];
      int cc = (ks & 1) * 32 + ((l >> 4) << 3);
#pragma unroll
      for (int mt = 0; mt < 4; ++mt) {
        short8 af = *(const short8*)&R[lx<64>(mt * 16 + (l & 15), cc)];
        acc1[mt] = __builtin_amdgcn_mfma_f32_16x16x32_bf16(af, bf, acc1[mt], 0, 0, 0);
      }
    }
  }
  __syncthreads();  // all reads done before Hs overlay
#pragma unroll
  for (int mt = 0; mt < 4; ++mt)
#pragma unroll
    for (int q = 0; q < 4; ++q) {
      int r = mt * 16 + (l >> 4) * 4 + q;
      Hs[lx<64>(r, w * 16 + (l & 15))] = f2b(silu_f(acc1[mt][q]));
    }
  __syncthreads();

  f32x4 acc2[4];
  {
    float bias = b2[w * 16 + (l & 15)];
#pragma unroll
    for (int mt = 0; mt < 4; ++mt) acc2[mt] = (f32x4){bias, bias, bias, bias};
    for (int ks = 0; ks < 2; ++ks) {
      short8 bf = *(const short8*)(Wp2 + ((size_t)(ks * 4 + w) * 64 + l) * 8);
#pragma unroll
      for (int mt = 0; mt < 4; ++mt) {
        short8 af = *(const short8*)&Hs[lx<64>(mt * 16 + (l & 15), ks * 32 + ((l >> 4) << 3))];
        acc2[mt] = __builtin_amdgcn_mfma_f32_16x16x32_bf16(af, bf, acc2[mt], 0, 0, 0);
      }
    }
  }
  __syncthreads();  // before OS overlay (S[1] dead)
#pragma unroll
  for (int mt = 0; mt < 4; ++mt)
#pragma unroll
    for (int q = 0; q < 4; ++q) {
      int r = mt * 16 + (l >> 4) * 4 + q;
      OS[lx<64>(r, w * 16 + (l & 15))] = f2b(acc2[mt][q]);
    }
  __syncthreads();
  for (int i = 0; i < 2; ++i) {
    int idx = i * 256 + tid;
    int r = idx >> 3, c0 = (idx & 7) << 3;
    uint4 val = *(const uint4*)&OS[lx<64>(r, c0)];
    *(uint4*)(tmsg_s + (size_t)(st0 + r) * 64 + c0) = val;
  }
}

// ---------------- Kernel M (MFMA + gload_lds staging): natural edge order -> msg_s[eslot]
__global__ __launch_bounds__(256) void kmsg_mfma(
    const int* __restrict__ eidx, const u16* __restrict__ s_bf,
    const u16* __restrict__ erbf_bf,
    const int* __restrict__ toff, const u16* __restrict__ tmsg_s,
    const int* __restrict__ eslot,
    const u16* __restrict__ Wp1, const float* __restrict__ b1,
    const u16* __restrict__ Wp2, const float* __restrict__ b2,
    u16* __restrict__ msg_s) {
  __shared__ __align__(16) u16 S[4][64 * 64];
  u16* Hs = &S[0][0];   // overlay after layer 1
  u16* OS = &S[1][0];   // out-stage [64][128] over S[1]+S[2]
  const int tid = threadIdx.x;
  const int l = tid & 63;
  const int w = tid >> 6;
  const int e0 = blockIdx.x * 64;

  {
    int wr = w * 16;
#pragma unroll
    for (int v = 0; v < 2; ++v) {
      int br = wr + v * 8;
      int r = br + (l >> 3);
      int sch = (l & 7) ^ (r & 7);
      gload16(s_bf + (size_t)eidx[e0 + r] * 64 + sch * 8, &S[0][br * 64]);
      gload16(s_bf + (size_t)eidx[NE + e0 + r] * 64 + sch * 8, &S[1][br * 64]);
      gload16(erbf_bf + (size_t)(e0 + r) * 64 + sch * 8, &S[2][br * 64]);
    }
  }
#pragma unroll
  for (int it = 0; it < 2; ++it) {
    int idx = it * 256 + tid;
    int r = idx >> 3, ch = idx & 7;
    int e = e0 + r;
    int r0 = toff[e], r1 = toff[e + 1];
    float a[8];
#pragma unroll
    for (int j = 0; j < 8; ++j) a[j] = 0.f;
    for (int ri = r0; ri < r1; ++ri) {
      uint4 pk = *(const uint4*)&tmsg_s[(size_t)ri * 64 + ch * 8];
      a[0] += b2f((u16)(pk.x & 0xffff)); a[1] += b2f((u16)(pk.x >> 16));
      a[2] += b2f((u16)(pk.y & 0xffff)); a[3] += b2f((u16)(pk.y >> 16));
      a[4] += b2f((u16)(pk.z & 0xffff)); a[5] += b2f((u16)(pk.z >> 16));
      a[6] += b2f((u16)(pk.w & 0xffff)); a[7] += b2f((u16)(pk.w >> 16));
    }
    uint4 p;
    p.x = pk2(a[0], a[1]);
    p.y = pk2(a[2], a[3]);
    p.z = pk2(a[4], a[5]);
    p.w = pk2(a[6], a[7]);
    *(uint4*)&S[3][lx<64>(r, ch * 8)] = p;
  }
  __syncthreads();

  f32x4 acc1[4];
  {
    float bias = b1[w * 16 + (l & 15)];
#pragma unroll
    for (int mt = 0; mt < 4; ++mt) acc1[mt] = (f32x4){bias, bias, bias, bias};
#pragma unroll
    for (int ks = 0; ks < 8; ++ks) {
      short8 bf = *(const short8*)(Wp1 + ((size_t)(ks * 4 + w) * 64 + l) * 8);
      const u16* R = &S[ks >> 1][0];
      int cc = (ks & 1) * 32 + ((l >> 4) << 3);
#pragma unroll
      for (int mt = 0; mt < 4; ++mt) {
        short8 af = *(const short8*)&R[lx<64>(mt * 16 + (l & 15), cc)];
        acc1[mt] = __builtin_amdgcn_mfma_f32_16x16x32_bf16(af, bf, acc1[mt], 0, 0, 0);
      }
    }
  }
  __syncthreads();
#pragma unroll
  for (int mt = 0; mt < 4; ++mt)
#pragma unroll
    for (int q = 0; q < 4; ++q) {
      int r = mt * 16 + (l >> 4) * 4 + q;
      Hs[lx<64>(r, w * 16 + (l & 15))] = f2b(silu_f(acc1[mt][q]));
    }
  __syncthreads();

  f32x4 acc2[2][4];
#pragma unroll
  for (int pp = 0; pp < 2; ++pp) {
    int nt = w * 2 + pp;
    float bias = b2[nt * 16 + (l & 15)];
#pragma unroll
    for (int mt = 0; mt < 4; ++mt) acc2[pp][mt] = (f32x4){bias, bias, bias, bias};
    for (int ks = 0; ks < 2; ++ks) {
      short8 bf = *(const short8*)(Wp2 + ((size_t)(ks * 8 + nt) * 64 + l) * 8);
#pragma unroll
      for (int mt = 0; mt < 4; ++mt) {
        short8 af = *(const short8*)&Hs[lx<64>(mt * 16 + (l & 15), ks * 32 + ((l >> 4) << 3))];
        acc2[pp][mt] = __builtin_amdgcn_mfma_f32_16x16x32_bf16(af, bf, acc2[pp][mt], 0, 0, 0);
      }
    }
  }
  __syncthreads();
#pragma unroll
  for (int pp = 0; pp < 2; ++pp)
#pragma unroll
    for (int mt = 0; mt < 4; ++mt)
#pragma unroll
      for (int q = 0; q < 4; ++q) {
        int r = mt * 16 + (l >> 4) * 4 + q;
        OS[lx<128>(r, (w * 2 + pp) * 16 + (l & 15))] = f2b(acc2[pp][mt][q]);
      }
  __syncthreads();
  for (int i = 0; i < 4; ++i) {
    int idx = i * 256 + tid;
    int r = idx >> 4, c0 = (idx & 15) << 3;
    int slot = eslot[e0 + r];
    uint4 val = *(const uint4*)&OS[lx<128>(r, c0)];
    *(uint4*)(msg_s + (size_t)slot * 128 + c0) = val;
  }
}

// ---------------- Kernel A: streaming CSR reduction; aggs + aggv both bf16
__global__ __launch_bounds__(256) void kagg(
    const int* __restrict__ noff, const u16* __restrict__ msg_s,
    const float* __restrict__ dir_s,
    u16* __restrict__ aggs_bf, u16* __restrict__ aggv_bf) {
  const int lane = threadIdx.x & 63;
  const int wv = threadIdx.x >> 6;
  const int n = blockIdx.x * 4 + wv;
  if (n >= NN) return;
  const int r0 = noff[n], r1 = noff[n + 1];
  const int lrow = lane >> 4, lcol = lane & 15;
  const bool is_ms = (lcol < 8);

  float a[8];
  float v0[8], v1[8], v2[8];
#pragma unroll
  for (int j = 0; j < 8; ++j) { a[j] = 0.f; v0[j] = 0.f; v1[j] = 0.f; v2[j] = 0.f; }

  for (int r4 = r0; r4 < r1; r4 += 4) {
    int r = r4 + lrow;
    if (r < r1) {
      uint4 pk = *(const uint4*)&msg_s[(size_t)r * 128 + lcol * 8];
      float x[8];
      x[0] = b2f((u16)(pk.x & 0xffff)); x[1] = b2f((u16)(pk.x >> 16));
      x[2] = b2f((u16)(pk.y & 0xffff)); x[3] = b2f((u16)(pk.y >> 16));
      x[4] = b2f((u16)(pk.z & 0xffff)); x[5] = b2f((u16)(pk.z >> 16));
      x[6] = b2f((u16)(pk.w & 0xffff)); x[7] = b2f((u16)(pk.w >> 16));
      if (is_ms) {
#pragma unroll
        for (int j = 0; j < 8; ++j) a[j] += x[j];
      } else {
        float dx = dir_s[(size_t)r * 3 + 0];
        float dy = dir_s[(size_t)r * 3 + 1];
        float dz = dir_s[(size_t)r * 3 + 2];
#pragma unroll
        for (int j = 0; j < 8; ++j) {
          v0[j] += x[j] * dx; v1[j] += x[j] * dy; v2[j] += x[j] * dz;
        }
      }
    }
  }
#pragma unroll
  for (int j = 0; j < 8; ++j) {
    a[j] += __shfl_xor(a[j], 16);  a[j] += __shfl_xor(a[j], 32);
    v0[j] += __shfl_xor(v0[j], 16); v0[j] += __shfl_xor(v0[j], 32);
    v1[j] += __shfl_xor(v1[j], 16); v1[j] += __shfl_xor(v1[j], 32);
    v2[j] += __shfl_xor(v2[j], 16); v2[j] += __shfl_xor(v2[j], 32);
  }
  if (lrow == 0) {
    if (is_ms) {
      uint4 p;
      p.x = pk2(a[0], a[1]);
      p.y = pk2(a[2], a[3]);
      p.z = pk2(a[4], a[5]);
      p.w = pk2(a[6], a[7]);
      *(uint4*)&aggs_bf[(size_t)n * 64 + lcol * 8] = p;
    } else {
      int c0 = (lcol - 8) * 8;
      // 24 contiguous bf16 = 3 uint4
      u16* av = aggv_bf + (size_t)n * 192 + (size_t)c0 * 3;
      uint4 q0, q1, q2;
      q0.x = pk2(v0[0], v1[0]); q0.y = pk2(v2[0], v0[1]);
      q0.z = pk2(v1[1], v2[1]); q0.w = pk2(v0[2], v1[2]);
      q1.x = pk2(v2[2], v0[3]); q1.y = pk2(v1[3], v2[3]);
      q1.z = pk2(v0[4], v1[4]); q1.w = pk2(v2[4], v0[5]);
      q2.x = pk2(v1[5], v2[5]); q2.y = pk2(v0[6], v1[6]);
      q2.z = pk2(v2[6], v0[7]); q2.w = pk2(v1[7], v2[7]);
      uint4* av4 = (uint4*)av;
      av4[0] = q0; av4[1] = q1; av4[2] = q2;
    }
  }
}

// ---------------- Kernel N (MFMA; aggv now bf16, unpacked in gate epilogue)
__global__ __launch_bounds__(256) void knode_mfma(
    const u16* __restrict__ s_bf, const float* __restrict__ v,
    const u16* __restrict__ aggs_bf, const u16* __restrict__ aggv_bf,
    const u16* __restrict__ WpU1, const float* __restrict__ bU1,
    const u16* __restrict__ WpU2, const float* __restrict__ bU2,
    const u16* __restrict__ WpG1, const float* __restrict__ bG1,
    const u16* __restrict__ WpG2, const float* __restrict__ bG2,
    const float* __restrict__ lng, const float* __restrict__ lnb,
    float* __restrict__ outs, float* __restrict__ outv) {
  __shared__ __align__(16) char smem[64 * 192 * 2 + 2 * 64 * 64 * 2];  // 40KB
  u16* Xs = (u16*)smem;
  u16* Hu = (u16*)(smem + 64 * 192 * 2);
  u16* Hg = Hu + 64 * 64;
  float* Fs = (float*)smem;

  const int tid = threadIdx.x;
  const int l = tid & 63;
  const int w = tid >> 6;
  const int n0 = blockIdx.x * 64;

  for (int i = 0; i < 2; ++i) {
    int idx = i * 256 + tid;
    int r = idx >> 3, c0 = (idx & 7) << 3;
    int nr = n0 + r; if (nr >= NN) nr = NN - 1;
    uint4 a = *(const uint4*)&s_bf[(size_t)nr * 64 + c0];
    *(uint4*)&Xs[lx<192>(r, c0)] = a;
    uint4 b = *(const uint4*)&aggs_bf[(size_t)nr * 64 + c0];
    *(uint4*)&Xs[lx<192>(r, 64 + c0)] = b;
  }
  for (int it = 0; it < 16; ++it) {
    int idx = it * 256 + tid;
    int r = idx >> 6, c = idx & 63;
    int nr = n0 + r; if (nr >= NN) nr = NN - 1;
    const float* vp = v + (size_t)nr * 192 + c * 3;
    float x = vp[0], y = vp[1], z = vp[2];
    Xs[lx<192>(r, 128 + c)] = f2b(sqrtf(x * x + y * y + z * z));
  }
  __syncthreads();

  f32x4 au[4], ag[4];
  {
    float biu = bU1[w * 16 + (l & 15)], big = bG1[w * 16 + (l & 15)];
#pragma unroll
    for (int mt = 0; mt < 4; ++mt) {
      au[mt] = (f32x4){biu, biu, biu, biu};
      ag[mt] = (f32x4){big, big, big, big};
    }
    for (int ks = 0; ks < 6; ++ks) {
      short8 bu = *(const short8*)(WpU1 + ((size_t)(ks * 4 + w) * 64 + l) * 8);
      short8 bg = *(const short8*)(WpG1 + ((size_t)(ks * 4 + w) * 64 + l) * 8);
#pragma unroll
      for (int mt = 0; mt < 4; ++mt) {
        short8 af = *(const short8*)&Xs[lx<192>(mt * 16 + (l & 15), ks * 32 + ((l >> 4) << 3))];
        au[mt] = __builtin_amdgcn_mfma_f32_16x16x32_bf16(af, bu, au[mt], 0, 0, 0);
        ag[mt] = __builtin_amdgcn_mfma_f32_16x16x32_bf16(af, bg, ag[mt], 0, 0, 0);
      }
    }
  }
#pragma unroll
  for (int mt = 0; mt < 4; ++mt)
#pragma unroll
    for (int q = 0; q < 4; ++q) {
      int r = mt * 16 + (l >> 4) * 4 + q;
      Hu[lx<64>(r, w * 16 + (l & 15))] = f2b(silu_f(au[mt][q]));
      Hg[lx<64>(r, w * 16 + (l & 15))] = f2b(silu_f(ag[mt][q]));
    }
  __syncthreads();

  f32x4 ou[4], og[4];
  {
    float biu = bU2[w * 16 + (l & 15)], big = bG2[w * 16 + (l & 15)];
#pragma unroll
    for (int mt = 0; mt < 4; ++mt) {
      ou[mt] = (f32x4){biu, biu, biu, biu};
      og[mt] = (f32x4){big, big, big, big};
    }
    for (int ks = 0; ks < 2; ++ks) {
      short8 bu = *(const short8*)(WpU2 + ((size_t)(ks * 4 + w) * 64 + l) * 8);
      short8 bg = *(const short8*)(WpG2 + ((size_t)(ks * 4 + w) * 64 + l) * 8);
#pragma unroll
      for (int mt = 0; mt < 4; ++mt) {
        short8 afu = *(const short8*)&Hu[lx<64>(mt * 16 + (l & 15), ks * 32 + ((l >> 4) << 3))];
        ou[mt] = __builtin_amdgcn_mfma_f32_16x16x32_bf16(afu, bu, ou[mt], 0, 0, 0);
        short8 afg = *(const short8*)&Hg[lx<64>(mt * 16 + (l & 15), ks * 32 + ((l >> 4) << 3))];
        og[mt] = __builtin_amdgcn_mfma_f32_16x16x32_bf16(afg, bg, og[mt], 0, 0, 0);
      }
    }
  }
#pragma unroll
  for (int mt = 0; mt < 4; ++mt)
#pragma unroll
    for (int q = 0; q < 4; ++q) {
      int r = mt * 16 + (l >> 4) * 4 + q;
      ou[mt][q] += b2f(Xs[lx<192>(r, w * 16 + (l & 15))]);
    }
  __syncthreads();

#pragma unroll
  for (int mt = 0; mt < 4; ++mt)
#pragma unroll
    for (int q = 0; q < 4; ++q) {
      int r = mt * 16 + (l >> 4) * 4 + q;
      Fs[r * 68 + w * 16 + (l & 15)] = ou[mt][q];
    }
  __syncthreads();
  {
    int r = tid >> 2, c0 = (tid & 3) * 16;
    float xv[16];
#pragma unroll
    for (int j4 = 0; j4 < 4; ++j4) {
      float4 t = *(const float4*)&Fs[r * 68 + c0 + j4 * 4];
      xv[j4 * 4 + 0] = t.x; xv[j4 * 4 + 1] = t.y;
      xv[j4 * 4 + 2] = t.z; xv[j4 * 4 + 3] = t.w;
    }
    float sm = 0.f, sq = 0.f;
#pragma unroll
    for (int j = 0; j < 16; ++j) { sm += xv[j]; sq += xv[j] * xv[j]; }
    sm += __shfl_xor(sm, 1); sq += __shfl_xor(sq, 1);
    sm += __shfl_xor(sm, 2); sq += __shfl_xor(sq, 2);
    float mu = sm * (1.f / 64.f);
    float var = sq * (1.f / 64.f) - mu * mu;
    float rstd = rsqrtf(var + 1e-5f);
    if (n0 + r < NN) {
      float* op = outs + (size_t)(n0 + r) * 64 + c0;
#pragma unroll
      for (int j4 = 0; j4 < 4; ++j4) {
        float4 o;
        float y0 = (xv[j4 * 4 + 0] - mu) * rstd * lng[c0 + j4 * 4 + 0] + lnb[c0 + j4 * 4 + 0];
        float y1 = (xv[j4 * 4 + 1] - mu) * rstd * lng[c0 + j4 * 4 + 1] + lnb[c0 + j4 * 4 + 1];
        float y2 = (xv[j4 * 4 + 2] - mu) * rstd * lng[c0 + j4 * 4 + 2] + lnb[c0 + j4 * 4 + 2];
        float y3 = (xv[j4 * 4 + 3] - mu) * rstd * lng[c0 + j4 * 4 + 3] + lnb[c0 + j4 * 4 + 3];
        o.x = silu_f(y0); o.y = silu_f(y1); o.z = silu_f(y2); o.w = silu_f(y3);
        *(float4*)(op + j4 * 4) = o;
      }
    }
  }
  __syncthreads();

#pragma unroll
  for (int mt = 0; mt < 4; ++mt)
#pragma unroll
    for (int q = 0; q < 4; ++q) {
      int r = mt * 16 + (l >> 4) * 4 + q;
      Fs[r * 68 + w * 16 + (l & 15)] = og[mt][q];
    }
  __syncthreads();
  {
    int r = tid >> 2, c0 = (tid & 3) * 16;
    int nr = n0 + r;
    if (nr < NN) {
      float gate[16];
#pragma unroll
      for (int j = 0; j < 16; ++j) gate[j] = sigm_f(Fs[r * 68 + c0 + j]);
      // unpack 48 bf16 aggv values
      const uint4* ab = (const uint4*)(aggv_bf + (size_t)nr * 192 + (size_t)c0 * 3);
      float avf[48];
#pragma unroll
      for (int j4 = 0; j4 < 6; ++j4) {
        uint4 pk = ab[j4];
        avf[j4 * 8 + 0] = b2f((u16)(pk.x & 0xffff)); avf[j4 * 8 + 1] = b2f((u16)(pk.x >> 16));
        avf[j4 * 8 + 2] = b2f((u16)(pk.y & 0xffff)); avf[j4 * 8 + 3] = b2f((u16)(pk.y >> 16));
        avf[j4 * 8 + 4] = b2f((u16)(pk.z & 0xffff)); avf[j4 * 8 + 5] = b2f((u16)(pk.z >> 16));
        avf[j4 * 8 + 6] = b2f((u16)(pk.w & 0xffff)); avf[j4 * 8 + 7] = b2f((u16)(pk.w >> 16));
      }
      const float4* vp = (const float4*)(v + (size_t)nr * 192 + c0 * 3);
      float4* op = (float4*)(outv + (size_t)nr * 192 + c0 * 3);
#pragma unroll
      for (int j4 = 0; j4 < 12; ++j4) {
        float4 vv = vp[j4], o;
        o.x = vv.x + gate[(j4 * 4 + 0) / 3] * avf[j4 * 4 + 0];
        o.y = vv.y + gate[(j4 * 4 + 1) / 3] * avf[j4 * 4 + 1];
        o.z = vv.z + gate[(j4 * 4 + 2) / 3] * avf[j4 * 4 + 2];
        o.w = vv.w + gate[(j4 * 4 + 3) / 3] * avf[j4 * 4 + 3];
        op[j4] = o;
      }
    }
  }
}

extern "C" void kernel_launch(void* const* d_in, const int* in_sizes, int n_in,
                              void* d_out, int out_size, void* d_ws, size_t ws_size,
                              hipStream_t stream) {
  const float* s     = (const float*)d_in[0];
  const float* v     = (const float*)d_in[1];
  const int*   eidx  = (const int*)d_in[2];
  const float* erbf  = (const float*)d_in[3];
  const float* edir  = (const float*)d_in[4];
  const int*   tkj   = (const int*)d_in[5];
  const int*   tji   = (const int*)d_in[6];
  const float* afeat = (const float*)d_in[7];
  const float* W_t1  = (const float*)d_in[8];
  const float* b_t1  = (const float*)d_in[9];
  const float* W_t2  = (const float*)d_in[10];
  const float* b_t2  = (const float*)d_in[11];
  const float* W_m1  = (const float*)d_in[12];
  const float* b_m1  = (const float*)d_in[13];
  const float* W_m2  = (const float*)d_in[14];
  const float* b_m2  = (const float*)d_in[15];
  const float* W_u1  = (const float*)d_in[16];
  const float* b_u1  = (const float*)d_in[17];
  const float* W_u2  = (const float*)d_in[18];
  const float* b_u2  = (const float*)d_in[19];
  const float* W_g1  = (const float*)d_in[20];
  const float* b_g1  = (const float*)d_in[21];
  const float* W_g2  = (const float*)d_in[22];
  const float* b_g2  = (const float*)d_in[23];
  const float* ln_g  = (const float*)d_in[24];
  const float* ln_b  = (const float*)d_in[25];

  char* w = (char*)d_ws;
  auto alloc = [&](size_t bytes) -> char* {
    char* p = w;
    w += (bytes + 255) & ~(size_t)255;
    return p;
  };
  int* tcnt  = (int*)alloc((size_t)NE * 4);
  int* ncnt  = (int*)alloc((size_t)NN * 4);
  size_t zspan = (size_t)((char*)(ncnt + NN) - (char*)tcnt);
  int* toff  = (int*)alloc((size_t)(NE + 1) * 4);
  int* noff  = (int*)alloc((size_t)(NN + 1) * 4);
  int* tids  = (int*)alloc((size_t)NT * 4);
  int* eslot = (int*)alloc((size_t)NE * 4);
  int* bsum  = (int*)alloc(2048 * 4);
  float* dir_s = (float*)alloc((size_t)NE * 3 * 4);
  u16* msg_s  = (u16*)alloc((size_t)NE * 128 * 2);       // 204.8 MB
  u16* tmsg_s = (u16*)alloc((size_t)NT * 64 * 2);        // 102.4 MB
  u16* erbf_bf = (u16*)alloc((size_t)NE * 64 * 2);       // 102.4 MB
  u16* s_bf    = (u16*)alloc((size_t)NN * 64 * 2);       // 6.4 MB
  u16* Wp_t1 = (u16*)alloc((size_t)5 * 4 * 512 * 2);
  u16* Wp_t2 = (u16*)alloc((size_t)2 * 4 * 512 * 2);
  u16* Wp_m1 = (u16*)alloc((size_t)8 * 4 * 512 * 2);
  u16* Wp_m2 = (u16*)alloc((size_t)2 * 8 * 512 * 2);
  u16* Wp_u1 = (u16*)alloc((size_t)6 * 4 * 512 * 2);
  u16* Wp_u2 = (u16*)alloc((size_t)2 * 4 * 512 * 2);
  u16* Wp_g1 = (u16*)alloc((size_t)6 * 4 * 512 * 2);
  u16* Wp_g2 = (u16*)alloc((size_t)2 * 4 * 512 * 2);
  // aggs_bf + aggv_bf alias tmsg_s (dead after kmsg): 6.4 + 19.2 = 25.6 <= 102.4 MB
  u16* aggs_bf = tmsg_s;
  u16* aggv_bf = tmsg_s + (size_t)NN * 64;

  hipMemsetAsync(tcnt, 0, zspan, stream);

  kcvt_hist<<<((NE + NN) * 16 + NT + NE + 255) / 256, 256, 0, stream>>>(
      erbf, erbf_bf, s, s_bf, tji, eidx + NE, tcnt, ncnt);

  const int Bt = (NE + 1023) / 1024, Bn = (NN + 1023) / 1024;
  kscan1b<<<Bt + Bn, 256, 0, stream>>>(tcnt, NE, toff, bsum, Bt, ncnt, NN, noff, bsum + 1024);
  kscan2b<<<2, 1024, 0, stream>>>(bsum, Bt, bsum + 1024, Bn);
  kscan3b<<<(NE + 1 + NN + 1 + 255) / 256, 256, 0, stream>>>(toff, bsum, NE, NT,
                                                             noff, bsum + 1024, NN, NE);

  kprep_all<<<(NT + NE + 140 * 64 + 255) / 256, 256, 0, stream>>>(
      tji, toff, tcnt, tids,
      eidx + NE, noff, ncnt, eslot, edir, dir_s,
      W_t1, W_t2, W_m1, W_m2, W_u1, W_u2, W_g1, W_g2,
      Wp_t1, Wp_t2, Wp_m1, Wp_m2, Wp_u1, Wp_u2, Wp_g1, Wp_g2);

  ktrip_mfma<<<NT / 64, 256, 0, stream>>>(tkj, tji, erbf_bf, afeat, tids,
                                          Wp_t1, b_t1, Wp_t2, b_t2, tmsg_s);
  kmsg_mfma<<<NE / 64, 256, 0, stream>>>(eidx, s_bf, erbf_bf, toff, tmsg_s, eslot,
                                         Wp_m1, b_m1, Wp_m2, b_m2, msg_s);
  kagg<<<(NN + 3) / 4, 256, 0, stream>>>(noff, msg_s, dir_s, aggs_bf, aggv_bf);

  float* out_s = (float*)d_out;
  float* out_v = out_s + (size_t)NN * 64;
  knode_mfma<<<(NN + 63) / 64, 256, 0, stream>>>(s_bf, v, aggs_bf, aggv_bf,
                                                 Wp_u1, b_u1, Wp_u2, b_u2,
                                                 Wp_g1, b_g1, Wp_g2, b_g2,
                                                 ln_g, ln_b, out_s, out_v);
}